// Round 4
// baseline (1337.457 us; speedup 1.0000x reference)
//
#include <hip/hip_runtime.h>
#include <hip/hip_bf16.h>
#include <math.h>

// Sizes from the reference
#define HDIM   256
#define NHEAD  4
#define LLAY   4
#define TLAY   4
#define KMAXC  10
#define MAXD   32
#define BATCH  64
#define MSUB   32
#define KNODE  32
#define SSUB   2048     // BATCH*MSUB
#define NNODE  65536    // SSUB*KNODE
#define NEDGE  131072
#define EPSPER 64       // NEDGE/SSUB
#define EDN    5

typedef unsigned short u16;   // raw bf16 bits (internal staging only)
typedef __attribute__((ext_vector_type(8))) short bf16x8;
typedef __attribute__((ext_vector_type(4))) float f32x4;

__device__ __forceinline__ float us2f(u16 u) {
    union { unsigned int i; float f; } x; x.i = ((unsigned int)u) << 16; return x.f;
}
__device__ __forceinline__ u16 f2us(float v) {
    union { float f; unsigned int i; } x; x.f = v;
    unsigned int u = x.i;
    u += 0x7fffu + ((u >> 16) & 1u);   // RNE
    return (u16)(u >> 16);
}
__device__ __forceinline__ float finite_or_zero(float v) {
    return (v == v && fabsf(v) <= 3.0e38f) ? v : 0.0f;
}
// async global->LDS, 16B per lane; lds base wave-uniform, lane deposits at +lane*16
__device__ __forceinline__ void gll16(const u16* g, u16* l) {
    __builtin_amdgcn_global_load_lds(
        (const __attribute__((address_space(1))) unsigned int*)g,
        (__attribute__((address_space(3))) unsigned int*)l, 16, 0, 0);
}

// ---------------------------------------------------------------------------
// h init: 4 rows/block, vectorized.
__global__ __launch_bounds__(256) void k_init_h(
    const int* __restrict__ x_ids, const int* __restrict__ dist,
    const int* __restrict__ nodes, const float* __restrict__ lp,
    const float* __restrict__ atom_emb, const float* __restrict__ dist_emb,
    const float* __restrict__ logp_W, const float* __restrict__ logp_b,
    u16* __restrict__ h)
{
    int n = blockIdx.x * 4 + (threadIdx.x >> 6);
    int c = (threadIdx.x & 63) * 4;
    float valid = (nodes[n] >= 0) ? 1.0f : 0.0f;
    float lpv = finite_or_zero(lp[n >> 5]);
    int dc = dist[n]; dc = dc < 0 ? 0 : (dc > MAXD ? MAXD : dc);
    float4 wv = *reinterpret_cast<const float4*>(logp_W + c);
    float4 bv = *reinterpret_cast<const float4*>(logp_b + c);
    float4 av = *reinterpret_cast<const float4*>(atom_emb + x_ids[n] * HDIM + c);
    float4 dv = *reinterpret_cast<const float4*>(dist_emb + dc * HDIM + c);
    float p0 = fmaxf(lpv * wv.x + bv.x, 0.f), p1 = fmaxf(lpv * wv.y + bv.y, 0.f);
    float p2 = fmaxf(lpv * wv.z + bv.z, 0.f), p3 = fmaxf(lpv * wv.w + bv.w, 0.f);
    ushort4 o = { f2us((av.x + dv.x + p0) * valid), f2us((av.y + dv.y + p1) * valid),
                  f2us((av.z + dv.z + p2) * valid), f2us((av.w + dv.w + p3) * valid) };
    *reinterpret_cast<ushort4*>(h + (size_t)n * HDIM + c) = o;
}

// ---------------------------------------------------------------------------
// Per-subgraph message passing; 128 threads, 2 cols/thread (uint loads).
// Writes z = (1+eps)*h + segment_sum(relu(h[src]+bond[eid]))
__global__ __launch_bounds__(128) void k_edge_z(
    const u16* __restrict__ h, const int* __restrict__ src,
    const int* __restrict__ dst, const int* __restrict__ eids,
    const float* __restrict__ bond_emb, const float* __restrict__ gnn_eps,
    int layer, u16* __restrict__ z)
{
    int s = blockIdx.x, t = threadIdx.x;
    __shared__ float agg[KNODE * HDIM];   // 32 KB
    __shared__ float bond[EDN * HDIM];    // 5 KB
    int c = t * 2;
    for (int r = 0; r < KNODE; ++r) { agg[r * HDIM + c] = 0.f; agg[r * HDIM + c + 1] = 0.f; }
    for (int b = 0; b < EDN; ++b) {
        bond[b * HDIM + c] = bond_emb[b * HDIM + c];
        bond[b * HDIM + c + 1] = bond_emb[b * HDIM + c + 1];
    }
    int e0 = s * EPSPER;
    for (int e = 0; e < EPSPER; ++e) {
        int ei = e0 + e;
        int sg = src[ei];
        int dl = dst[ei] - s * KNODE;
        int be = eids[ei];
        unsigned int hv = *reinterpret_cast<const unsigned int*>(h + (size_t)sg * HDIM + c);
        float m0 = us2f((u16)(hv & 0xffff)) + bond[be * HDIM + c];
        float m1 = us2f((u16)(hv >> 16)) + bond[be * HDIM + c + 1];
        agg[dl * HDIM + c]     += m0 > 0.f ? m0 : 0.f;
        agg[dl * HDIM + c + 1] += m1 > 0.f ? m1 : 0.f;
    }
    float ep1 = 1.0f + gnn_eps[layer];
    for (int r = 0; r < KNODE; ++r) {
        size_t n = (size_t)(s * KNODE + r) * HDIM + c;
        unsigned int hv = *reinterpret_cast<const unsigned int*>(h + n);
        ushort2 o = { f2us(ep1 * us2f((u16)(hv & 0xffff)) + agg[r * HDIM + c]),
                      f2us(ep1 * us2f((u16)(hv >> 16)) + agg[r * HDIM + c + 1]) };
        *reinterpret_cast<ushort2*>(z + n) = o;
    }
}

// ---------------------------------------------------------------------------
// B-resident MFMA GEMM for K==256: C = epi(A @ B + bias).
// A: Mx256 bf16 (ws). B: 256xN f32 weights -> per-block LDS B^T panels.
// Block: 256 thr, 128x128 tile; A staged via global_load_lds, double-buffered.
// Bs panel layout: el(n,k) at [(k>>3)*128*8 + n*8 + (k&7)] -> conflict-free
// 16B writes (lanes n-consecutive) and k-contiguous bf16x8 frag reads.
__global__ __launch_bounds__(256) void k_bgemm(
    const u16* __restrict__ A, const float* __restrict__ B,
    const float* __restrict__ bias, void* __restrict__ Cout, int c_is_bf16,
    const float* __restrict__ resid, const int* __restrict__ valid,
    int M, int N, int act)
{
    const int K = 256;
    __shared__ __align__(16) u16 As[2][128 * 32];   // 16 KB
    __shared__ __align__(16) u16 Bs[32 * 128 * 8];  // 64 KB
    int tid = threadIdx.x;
    int lane = tid & 63, wave = tid >> 6;
    int wm = wave >> 1, wn = wave & 1;
    int bm = blockIdx.y * 128, bn = blockIdx.x * 128;

    // --- issue A(0) async, then build Bs ---
    {
        const u16* gA = A + (size_t)(bm + (lane >> 2)) * K + (lane & 3) * 8;
        #pragma unroll
        for (int t = 0; t < 2; ++t) {
            int seg = wave * 2 + t;
            gll16(gA + (size_t)seg * 16 * K, &As[0][seg * 512]);
        }
    }
    {
        int nb = tid & 127;
        int kh = (tid >> 7) * 128;
        for (int kb = kh; kb < kh + 128; kb += 8) {
            union { u16 s[8]; uint4 v; } tw;
            #pragma unroll
            for (int j = 0; j < 8; ++j)
                tw.s[j] = f2us(B[(size_t)(kb + j) * N + bn + nb]);
            *reinterpret_cast<uint4*>(&Bs[((kb >> 3) * 128 + nb) * 8]) = tw.v;
        }
    }
    __syncthreads();

    f32x4 acc[4][4];
    #pragma unroll
    for (int i = 0; i < 4; ++i)
        #pragma unroll
        for (int j = 0; j < 4; ++j)
            acc[i][j] = (f32x4){0.f, 0.f, 0.f, 0.f};

    int fr = lane & 15, quad = lane >> 4;
    for (int it = 0; it < 8; ++it) {
        int k0 = it * 32, buf = it & 1;
        if (it < 7) {
            const u16* gA = A + (size_t)(bm + (lane >> 2)) * K + (k0 + 32) + (lane & 3) * 8;
            #pragma unroll
            for (int t = 0; t < 2; ++t) {
                int seg = wave * 2 + t;
                gll16(gA + (size_t)seg * 16 * K, &As[buf ^ 1][seg * 512]);
            }
        }
        bf16x8 af[4], bfr[4];
        #pragma unroll
        for (int i = 0; i < 4; ++i)
            af[i] = *reinterpret_cast<const bf16x8*>(&As[buf][(wm * 64 + i * 16 + fr) * 32 + quad * 8]);
        int pq = (k0 >> 3) + quad;
        #pragma unroll
        for (int j = 0; j < 4; ++j)
            bfr[j] = *reinterpret_cast<const bf16x8*>(&Bs[(pq * 128 + wn * 64 + j * 16 + fr) * 8]);
        #pragma unroll
        for (int i = 0; i < 4; ++i)
            #pragma unroll
            for (int j = 0; j < 4; ++j)
                acc[i][j] = __builtin_amdgcn_mfma_f32_16x16x32_bf16(af[i], bfr[j], acc[i][j], 0, 0, 0);
        __syncthreads();
    }

    int crow0 = bm + wm * 64 + quad * 4;
    int ccol0 = bn + wn * 64 + fr;
    #pragma unroll
    for (int i = 0; i < 4; ++i) {
        #pragma unroll
        for (int r = 0; r < 4; ++r) {
            int m = crow0 + i * 16 + r;
            float vm = valid ? ((valid[m] >= 0) ? 1.0f : 0.0f) : 1.0f;
            #pragma unroll
            for (int j = 0; j < 4; ++j) {
                int n = ccol0 + j * 16;
                float v = acc[i][j][r];
                if (bias) v += bias[n];
                if (act == 1) v = v > 0.f ? v : 0.f;
                else if (act == 2) v = 0.5f * v * (1.0f + erff(v * 0.70710678118654752f));
                v *= vm;
                if (resid) v += resid[(size_t)m * N + n];
                if (c_is_bf16) ((u16*)Cout)[(size_t)m * N + n] = f2us(v);
                else ((float*)Cout)[(size_t)m * N + n] = v;
            }
        }
    }
}

// ---------------------------------------------------------------------------
// Generic MFMA GEMM (kept for K=1024 f2): on-the-fly B convert per tile.
__global__ __launch_bounds__(256) void k_mgemm(
    const u16* __restrict__ A, const float* __restrict__ B,
    const float* __restrict__ bias, void* __restrict__ Cout, int c_is_bf16,
    const float* __restrict__ resid, const int* __restrict__ valid,
    int M, int K, int N, int act)
{
    __shared__ __align__(16) u16 As[128][40];
    __shared__ __align__(16) u16 Bs[128][40];
    int tid = threadIdx.x;
    int lane = tid & 63, wave = tid >> 6;
    int wm = wave >> 1, wn = wave & 1;
    int bm = blockIdx.y * 128, bn = blockIdx.x * 128;
    f32x4 acc[4][4];
    #pragma unroll
    for (int i = 0; i < 4; ++i)
        #pragma unroll
        for (int j = 0; j < 4; ++j)
            acc[i][j] = (f32x4){0.f, 0.f, 0.f, 0.f};
    int arow = tid >> 1, akoff = (tid & 1) * 16;
    int tn = (tid & 31) * 4, tk = (tid >> 5) * 4;
    int fr = lane & 15, fk = (lane >> 4) * 8;
    for (int k0 = 0; k0 < K; k0 += 32) {
        const uint4* gA = reinterpret_cast<const uint4*>(A + (size_t)(bm + arow) * K + k0 + akoff);
        uint4 a0 = gA[0], a1 = gA[1];
        const float* gB = B + (size_t)(k0 + tk) * N + bn + tn;
        float4 r0 = *reinterpret_cast<const float4*>(gB);
        float4 r1 = *reinterpret_cast<const float4*>(gB + N);
        float4 r2 = *reinterpret_cast<const float4*>(gB + 2 * (size_t)N);
        float4 r3 = *reinterpret_cast<const float4*>(gB + 3 * (size_t)N);
        *reinterpret_cast<uint4*>(&As[arow][akoff]) = a0;
        *reinterpret_cast<uint4*>(&As[arow][akoff + 8]) = a1;
        ushort4 w0 = { f2us(r0.x), f2us(r1.x), f2us(r2.x), f2us(r3.x) };
        ushort4 w1 = { f2us(r0.y), f2us(r1.y), f2us(r2.y), f2us(r3.y) };
        ushort4 w2 = { f2us(r0.z), f2us(r1.z), f2us(r2.z), f2us(r3.z) };
        ushort4 w3 = { f2us(r0.w), f2us(r1.w), f2us(r2.w), f2us(r3.w) };
        *reinterpret_cast<ushort4*>(&Bs[tn + 0][tk]) = w0;
        *reinterpret_cast<ushort4*>(&Bs[tn + 1][tk]) = w1;
        *reinterpret_cast<ushort4*>(&Bs[tn + 2][tk]) = w2;
        *reinterpret_cast<ushort4*>(&Bs[tn + 3][tk]) = w3;
        __syncthreads();
        bf16x8 af[4], bfr[4];
        #pragma unroll
        for (int i = 0; i < 4; ++i)
            af[i] = *reinterpret_cast<const bf16x8*>(&As[wm * 64 + i * 16 + fr][fk]);
        #pragma unroll
        for (int j = 0; j < 4; ++j)
            bfr[j] = *reinterpret_cast<const bf16x8*>(&Bs[wn * 64 + j * 16 + fr][fk]);
        #pragma unroll
        for (int i = 0; i < 4; ++i)
            #pragma unroll
            for (int j = 0; j < 4; ++j)
                acc[i][j] = __builtin_amdgcn_mfma_f32_16x16x32_bf16(af[i], bfr[j], acc[i][j], 0, 0, 0);
        __syncthreads();
    }
    int crow0 = bm + wm * 64 + (lane >> 4) * 4;
    int ccol0 = bn + wn * 64 + (lane & 15);
    #pragma unroll
    for (int i = 0; i < 4; ++i) {
        #pragma unroll
        for (int r = 0; r < 4; ++r) {
            int m = crow0 + i * 16 + r;
            float vm = valid ? ((valid[m] >= 0) ? 1.0f : 0.0f) : 1.0f;
            #pragma unroll
            for (int j = 0; j < 4; ++j) {
                int n = ccol0 + j * 16;
                float v = acc[i][j][r];
                if (bias) v += bias[n];
                if (act == 1) v = v > 0.f ? v : 0.f;
                else if (act == 2) v = 0.5f * v * (1.0f + erff(v * 0.70710678118654752f));
                v *= vm;
                if (resid) v += resid[(size_t)m * N + n];
                if (c_is_bf16) ((u16*)Cout)[(size_t)m * N + n] = f2us(v);
                else ((float*)Cout)[(size_t)m * N + n] = v;
            }
        }
    }
}

// ---------------------------------------------------------------------------
// Row LayerNorm: 4 rows/block (one per wave), reads f32 x, writes bf16.
__global__ __launch_bounds__(256) void k_ln(
    const float* __restrict__ X, u16* __restrict__ Out,
    const float* __restrict__ g, const float* __restrict__ b)
{
    int row = blockIdx.x * 4 + (threadIdx.x >> 6);
    int lane = threadIdx.x & 63;
    float4 xv = *reinterpret_cast<const float4*>(X + (size_t)row * HDIM + lane * 4);
    float s = xv.x + xv.y + xv.z + xv.w;
    #pragma unroll
    for (int off = 32; off > 0; off >>= 1) s += __shfl_xor(s, off);
    float mu = s * (1.0f / HDIM);
    float d0 = xv.x - mu, d1 = xv.y - mu, d2 = xv.z - mu, d3 = xv.w - mu;
    float sq = d0 * d0 + d1 * d1 + d2 * d2 + d3 * d3;
    #pragma unroll
    for (int off = 32; off > 0; off >>= 1) sq += __shfl_xor(sq, off);
    float rs = rsqrtf(sq * (1.0f / HDIM) + 1e-5f);
    int c = lane * 4;
    float4 gv = *reinterpret_cast<const float4*>(g + c);
    float4 bv = *reinterpret_cast<const float4*>(b + c);
    ushort4 o = { f2us(d0 * rs * gv.x + bv.x), f2us(d1 * rs * gv.y + bv.y),
                  f2us(d2 * rs * gv.z + bv.z), f2us(d3 * rs * gv.w + bv.w) };
    *reinterpret_cast<ushort4*>(Out + (size_t)row * HDIM + c) = o;
}

// ---------------------------------------------------------------------------
// Overlap bias via 512-bit LDS bitmaps (node ids < 500).
__global__ __launch_bounds__(1024) void k_bias(
    const int* __restrict__ nodes, const float* __restrict__ lp,
    const float* __restrict__ ovl_emb, const float* __restrict__ alpha_p,
    float* __restrict__ bias)
{
    int b = blockIdx.x, tid = threadIdx.x;   // 1024 threads
    __shared__ int nd[32][32];
    __shared__ unsigned int bmv[32][17];
    __shared__ float lpc[32];
    __shared__ float emb[16];
    nd[tid >> 5][tid & 31] = nodes[b * 1024 + tid];
    if (tid < 512) bmv[tid >> 4][tid & 15] = 0u;
    if (tid < 32) {
        float l = finite_or_zero(lp[b * 32 + tid]);
        l = l < -30.f ? -30.f : (l > 0.f ? 0.f : l);
        lpc[tid] = l;
    }
    if (tid >= 64 && tid < 64 + KMAXC + 1) emb[tid - 64] = ovl_emb[tid - 64];
    __syncthreads();
    int own = nd[tid >> 5][tid & 31];
    if (own >= 0) atomicOr(&bmv[tid >> 5][own >> 5], 1u << (own & 31));
    __syncthreads();
    int i = tid >> 5, j = tid & 31;
    float alpha = alpha_p[0];
    int cnt = 0;
    #pragma unroll
    for (int k = 0; k < 32; ++k) {
        int nk = nd[i][k];
        if (nk >= 0) cnt += (int)((bmv[j][nk >> 5] >> (nk & 31)) & 1u);
    }
    bias[b * 1024 + tid] = emb[cnt > KMAXC ? KMAXC : cnt] - alpha * lpc[j];
}

// ---------------------------------------------------------------------------
__global__ __launch_bounds__(256) void k_gather(const u16* __restrict__ h, float* __restrict__ x)
{
    int s = blockIdx.x, c = threadIdx.x;
    x[(size_t)s * HDIM + c] = us2f(h[(size_t)s * KNODE * HDIM + c]);
}

// ---------------------------------------------------------------------------
// Attention for one (batch b, head hh): 32x32 scores with bias, softmax, PV.
__global__ __launch_bounds__(256) void k_attn(
    const u16* __restrict__ qkv, const float* __restrict__ bias, u16* __restrict__ o)
{
    int b = blockIdx.x >> 2, hh = blockIdx.x & 3;
    __shared__ float qs[32][65], ks[32][65], vs[32][65];
    __shared__ float sc[32][33];
    int tid = threadIdx.x;
    #pragma unroll
    for (int u = 0; u < 8; ++u) {
        int idx = tid + u * 256;
        int i = idx >> 6, d = idx & 63;
        size_t base = (size_t)(b * 32 + i) * 768;
        qs[i][d] = us2f(qkv[base + hh * 64 + d]);
        ks[i][d] = us2f(qkv[base + 256 + hh * 64 + d]);
        vs[i][d] = us2f(qkv[base + 512 + hh * 64 + d]);
    }
    __syncthreads();
    #pragma unroll
    for (int u = 0; u < 4; ++u) {
        int p = tid + u * 256;
        int i = p >> 5, j = p & 31;
        float s = 0.f;
        #pragma unroll
        for (int d = 0; d < 64; ++d) s += qs[i][d] * ks[j][d];
        sc[i][j] = s * 0.125f + bias[b * 1024 + i * 32 + j];
    }
    __syncthreads();
    if (tid < 32) {
        int i = tid;
        float m = -1e30f;
        for (int j = 0; j < 32; ++j) m = fmaxf(m, sc[i][j]);
        float sum = 0.f;
        for (int j = 0; j < 32; ++j) { float e = expf(sc[i][j] - m); sc[i][j] = e; sum += e; }
        float inv = 1.0f / sum;
        for (int j = 0; j < 32; ++j) sc[i][j] *= inv;
    }
    __syncthreads();
    #pragma unroll
    for (int u = 0; u < 8; ++u) {
        int idx = tid + u * 256;
        int i = idx >> 6, d = idx & 63;
        float a = 0.f;
        #pragma unroll
        for (int j = 0; j < 32; ++j) a += sc[i][j] * vs[j][d];
        o[(size_t)(b * 32 + i) * HDIM + hh * 64 + d] = f2us(a);
    }
}

// ---------------------------------------------------------------------------
// out[b] = sum_i softmax(-lp_c)[i] * xln[b,i,:]  (f32 output)
__global__ __launch_bounds__(256) void k_final(
    const u16* __restrict__ xln, const float* __restrict__ lp, float* __restrict__ out)
{
    int b = blockIdx.x, tid = threadIdx.x;
    __shared__ float w[32];
    if (tid < 32) {
        float l = finite_or_zero(lp[b * 32 + tid]);
        l = l < -30.f ? -30.f : (l > 0.f ? 0.f : l);
        w[tid] = -l;
    }
    __syncthreads();
    if (tid == 0) {
        float m = -1e30f;
        for (int i = 0; i < 32; ++i) m = fmaxf(m, w[i]);
        float s = 0.f;
        for (int i = 0; i < 32; ++i) { float e = expf(w[i] - m); w[i] = e; s += e; }
        float inv = 1.0f / s;
        for (int i = 0; i < 32; ++i) w[i] *= inv;
    }
    __syncthreads();
    float acc = 0.f;
    for (int i = 0; i < 32; ++i) acc += w[i] * us2f(xln[(size_t)(b * 32 + i) * HDIM + tid]);
    out[b * HDIM + tid] = acc;
}

// ---------------------------------------------------------------------------
extern "C" void kernel_launch(void* const* d_in, const int* in_sizes, int n_in,
                              void* d_out, int out_size, void* d_ws, size_t ws_size,
                              hipStream_t stream)
{
    const int*   x_ids    = (const int*)d_in[0];
    const int*   edge_ids = (const int*)d_in[1];
    const int*   srcp     = (const int*)d_in[2];
    const int*   dstp     = (const int*)d_in[3];
    const int*   nodes    = (const int*)d_in[4];
    const int*   dist     = (const int*)d_in[5];
    const float* lp       = (const float*)d_in[6];
    const float* atom_emb = (const float*)d_in[7];
    const float* bond_emb = (const float*)d_in[8];
    const float* dist_emb = (const float*)d_in[9];
    const float* logp_W   = (const float*)d_in[10];
    const float* logp_b   = (const float*)d_in[11];
    const float* gnn_eps  = (const float*)d_in[12];
    const float* gnn_W1   = (const float*)d_in[13];
    const float* gnn_b1   = (const float*)d_in[14];
    const float* gnn_W2   = (const float*)d_in[15];
    const float* gnn_b2   = (const float*)d_in[16];
    const float* ln1_g    = (const float*)d_in[17];
    const float* ln1_b    = (const float*)d_in[18];
    const float* qkv_W    = (const float*)d_in[19];
    const float* out_W    = (const float*)d_in[20];
    const float* out_b    = (const float*)d_in[21];
    const float* ln2_g    = (const float*)d_in[22];
    const float* ln2_b    = (const float*)d_in[23];
    const float* f1_W     = (const float*)d_in[24];
    const float* f1_b     = (const float*)d_in[25];
    const float* f2_W     = (const float*)d_in[26];
    const float* f2_b     = (const float*)d_in[27];
    const float* lnout_g  = (const float*)d_in[28];
    const float* lnout_b  = (const float*)d_in[29];
    const float* ovl_emb  = (const float*)d_in[30];
    const float* alpha    = (const float*)d_in[31];

    // Workspace layout (96 MB total):
    //   [0,32M)    h   bf16 NNODE*H
    //   [32,64M)   z   bf16 (GNN); transformer scratch aliases here after GNN
    //   [64,96M)   zr  bf16 (GNN); x (f32) aliases here in transformer phase
    char* ws = (char*)d_ws;
    u16*   h     = (u16*)(ws);
    u16*   z     = (u16*)(ws + 33554432ull);
    u16*   zr    = (u16*)(ws + 67108864ull);
    // transformer phase (z/zr regions are dead):
    u16*   r     = (u16*)(ws + 33554432ull);                 // 1 MB
    u16*   ob    = (u16*)(ws + 33554432ull + 1048576ull);    // 1 MB
    u16*   qkvb  = (u16*)(ws + 33554432ull + 2097152ull);    // 3 MB
    u16*   ffh   = (u16*)(ws + 33554432ull + 5242880ull);    // 4 MB
    u16*   xln   = (u16*)(ws + 33554432ull + 9437184ull);    // 1 MB
    float* biasb = (float*)(ws + 33554432ull + 10485760ull); // 256 KB
    float* x     = (float*)(ws + 67108864ull);               // 2 MB f32

    k_init_h<<<NNODE / 4, 256, 0, stream>>>(x_ids, dist, nodes, lp, atom_emb, dist_emb,
                                            logp_W, logp_b, h);
    for (int l = 0; l < LLAY; ++l) {
        k_edge_z<<<SSUB, 128, 0, stream>>>(h, srcp, dstp, edge_ids, bond_emb, gnn_eps, l, z);
        k_bgemm<<<dim3(HDIM / 128, NNODE / 128), 256, 0, stream>>>(
            z, gnn_W1 + l * HDIM * HDIM, gnn_b1 + l * HDIM, zr, 1,
            nullptr, nullptr, NNODE, HDIM, 1);
        k_bgemm<<<dim3(HDIM / 128, NNODE / 128), 256, 0, stream>>>(
            zr, gnn_W2 + l * HDIM * HDIM, gnn_b2 + l * HDIM, h, 1,
            nullptr, nodes, NNODE, HDIM, 0);
    }
    k_bias<<<BATCH, 1024, 0, stream>>>(nodes, lp, ovl_emb, alpha, biasb);
    k_gather<<<SSUB, 256, 0, stream>>>(h, x);
    for (int t = 0; t < TLAY; ++t) {
        k_ln<<<SSUB / 4, 256, 0, stream>>>(x, r, ln1_g + t * HDIM, ln1_b + t * HDIM);
        k_bgemm<<<dim3(768 / 128, SSUB / 128), 256, 0, stream>>>(
            r, qkv_W + t * HDIM * 768, nullptr, qkvb, 1,
            nullptr, nullptr, SSUB, 768, 0);
        k_attn<<<BATCH * NHEAD, 256, 0, stream>>>(qkvb, biasb, ob);
        k_bgemm<<<dim3(HDIM / 128, SSUB / 128), 256, 0, stream>>>(
            ob, out_W + t * HDIM * HDIM, out_b + t * HDIM, x, 0,
            x, nullptr, SSUB, HDIM, 0);
        k_ln<<<SSUB / 4, 256, 0, stream>>>(x, r, ln2_g + t * HDIM, ln2_b + t * HDIM);
        k_bgemm<<<dim3(1024 / 128, SSUB / 128), 256, 0, stream>>>(
            r, f1_W + t * HDIM * 1024, f1_b + t * 1024, ffh, 1,
            nullptr, nullptr, SSUB, 1024, 2);
        k_mgemm<<<dim3(HDIM / 128, SSUB / 128), 256, 0, stream>>>(
            ffh, f2_W + t * 1024 * HDIM, f2_b + t * HDIM, x, 0,
            x, nullptr, SSUB, 1024, HDIM, 0);
    }
    k_ln<<<SSUB / 4, 256, 0, stream>>>(x, xln, lnout_g, lnout_b);
    k_final<<<BATCH, 256, 0, stream>>>(xln, lp, (float*)d_out);
}

// Round 5
// 1162.070 us; speedup vs baseline: 1.1509x; 1.1509x over previous
//
#include <hip/hip_runtime.h>
#include <hip/hip_bf16.h>
#include <math.h>

// Sizes from the reference
#define HDIM   256
#define NHEAD  4
#define LLAY   4
#define TLAY   4
#define KMAXC  10
#define MAXD   32
#define BATCH  64
#define MSUB   32
#define KNODE  32
#define SSUB   2048     // BATCH*MSUB
#define NNODE  65536    // SSUB*KNODE
#define NEDGE  131072
#define EPSPER 64       // NEDGE/SSUB
#define EDN    5

typedef unsigned short u16;   // raw bf16 bits (internal staging only)
typedef __attribute__((ext_vector_type(8))) short bf16x8;
typedef __attribute__((ext_vector_type(4))) float f32x4;

__device__ __forceinline__ float us2f(u16 u) {
    union { unsigned int i; float f; } x; x.i = ((unsigned int)u) << 16; return x.f;
}
__device__ __forceinline__ u16 f2us(float v) {
    union { float f; unsigned int i; } x; x.f = v;
    unsigned int u = x.i;
    u += 0x7fffu + ((u >> 16) & 1u);   // RNE
    return (u16)(u >> 16);
}
__device__ __forceinline__ float finite_or_zero(float v) {
    return (v == v && fabsf(v) <= 3.0e38f) ? v : 0.0f;
}
// async global->LDS, 16B per lane; lds base wave-uniform, lane deposits at +lane*16
__device__ __forceinline__ void gll16(const u16* g, u16* l) {
    __builtin_amdgcn_global_load_lds(
        (const __attribute__((address_space(1))) unsigned int*)g,
        (__attribute__((address_space(3))) unsigned int*)l, 16, 0, 0);
}

// ---------------------------------------------------------------------------
// Weight transpose+convert: W (K x N f32, slice z) -> WT (N x K bf16).
__global__ __launch_bounds__(256) void k_wtrans(
    const float* __restrict__ W, u16* __restrict__ WT, int K, int N)
{
    __shared__ float til[32][33];
    int k0 = blockIdx.x * 32, n0 = blockIdx.y * 32, s = blockIdx.z;
    const float* Wb = W + (size_t)s * K * N;
    u16* Tb = WT + (size_t)s * N * K;
    int j = threadIdx.x & 31, i0 = threadIdx.x >> 5;
    #pragma unroll
    for (int it = 0; it < 4; ++it) {
        int i = i0 + it * 8;
        til[i][j] = Wb[(size_t)(k0 + i) * N + n0 + j];
    }
    __syncthreads();
    #pragma unroll
    for (int it = 0; it < 4; ++it) {
        int i = i0 + it * 8;
        Tb[(size_t)(n0 + i) * K + k0 + j] = f2us(til[j][i]);
    }
}

// ---------------------------------------------------------------------------
// h init: 4 rows/block, vectorized.
__global__ __launch_bounds__(256) void k_init_h(
    const int* __restrict__ x_ids, const int* __restrict__ dist,
    const int* __restrict__ nodes, const float* __restrict__ lp,
    const float* __restrict__ atom_emb, const float* __restrict__ dist_emb,
    const float* __restrict__ logp_W, const float* __restrict__ logp_b,
    u16* __restrict__ h)
{
    int n = blockIdx.x * 4 + (threadIdx.x >> 6);
    int c = (threadIdx.x & 63) * 4;
    float valid = (nodes[n] >= 0) ? 1.0f : 0.0f;
    float lpv = finite_or_zero(lp[n >> 5]);
    int dc = dist[n]; dc = dc < 0 ? 0 : (dc > MAXD ? MAXD : dc);
    float4 wv = *reinterpret_cast<const float4*>(logp_W + c);
    float4 bv = *reinterpret_cast<const float4*>(logp_b + c);
    float4 av = *reinterpret_cast<const float4*>(atom_emb + x_ids[n] * HDIM + c);
    float4 dv = *reinterpret_cast<const float4*>(dist_emb + dc * HDIM + c);
    float p0 = fmaxf(lpv * wv.x + bv.x, 0.f), p1 = fmaxf(lpv * wv.y + bv.y, 0.f);
    float p2 = fmaxf(lpv * wv.z + bv.z, 0.f), p3 = fmaxf(lpv * wv.w + bv.w, 0.f);
    ushort4 o = { f2us((av.x + dv.x + p0) * valid), f2us((av.y + dv.y + p1) * valid),
                  f2us((av.z + dv.z + p2) * valid), f2us((av.w + dv.w + p3) * valid) };
    *reinterpret_cast<ushort4*>(h + (size_t)n * HDIM + c) = o;
}

// ---------------------------------------------------------------------------
// Per-subgraph message passing; 128 threads, 2 cols/thread (uint loads).
// Writes z = (1+eps)*h + segment_sum(relu(h[src]+bond[eid]))
__global__ __launch_bounds__(128) void k_edge_z(
    const u16* __restrict__ h, const int* __restrict__ src,
    const int* __restrict__ dst, const int* __restrict__ eids,
    const float* __restrict__ bond_emb, const float* __restrict__ gnn_eps,
    int layer, u16* __restrict__ z)
{
    int s = blockIdx.x, t = threadIdx.x;
    __shared__ float agg[KNODE * HDIM];   // 32 KB
    __shared__ float bond[EDN * HDIM];    // 5 KB
    int c = t * 2;
    for (int r = 0; r < KNODE; ++r) { agg[r * HDIM + c] = 0.f; agg[r * HDIM + c + 1] = 0.f; }
    for (int b = 0; b < EDN; ++b) {
        bond[b * HDIM + c] = bond_emb[b * HDIM + c];
        bond[b * HDIM + c + 1] = bond_emb[b * HDIM + c + 1];
    }
    int e0 = s * EPSPER;
    for (int e = 0; e < EPSPER; ++e) {
        int ei = e0 + e;
        int sg = src[ei];
        int dl = dst[ei] - s * KNODE;
        int be = eids[ei];
        unsigned int hv = *reinterpret_cast<const unsigned int*>(h + (size_t)sg * HDIM + c);
        float m0 = us2f((u16)(hv & 0xffff)) + bond[be * HDIM + c];
        float m1 = us2f((u16)(hv >> 16)) + bond[be * HDIM + c + 1];
        agg[dl * HDIM + c]     += m0 > 0.f ? m0 : 0.f;
        agg[dl * HDIM + c + 1] += m1 > 0.f ? m1 : 0.f;
    }
    float ep1 = 1.0f + gnn_eps[layer];
    for (int r = 0; r < KNODE; ++r) {
        size_t n = (size_t)(s * KNODE + r) * HDIM + c;
        unsigned int hv = *reinterpret_cast<const unsigned int*>(h + n);
        ushort2 o = { f2us(ep1 * us2f((u16)(hv & 0xffff)) + agg[r * HDIM + c]),
                      f2us(ep1 * us2f((u16)(hv >> 16)) + agg[r * HDIM + c + 1]) };
        *reinterpret_cast<ushort2*>(z + n) = o;
    }
}

// ---------------------------------------------------------------------------
// Pure-bf16 MFMA GEMM (m97 structure): C = epi(A @ BT^T + bias).
// A: MxK bf16 row-major. BT: NxK bf16 row-major (pre-transposed weights).
// 128x128 tile, 4 waves (2x2), 16x16x32 MFMA, both tiles staged via
// global_load_lds width-16, double-buffered. K%32==0, M%128==0, N%128==0.
__global__ __launch_bounds__(256) void k_tgemm(
    const u16* __restrict__ A, const u16* __restrict__ BT,
    const float* __restrict__ bias, void* __restrict__ Cout, int c_is_bf16,
    const float* __restrict__ resid, const int* __restrict__ valid,
    int M, int K, int N, int act)
{
    __shared__ __align__(16) u16 As[2][128 * 32];   // 16 KB
    __shared__ __align__(16) u16 Bs[2][128 * 32];   // 16 KB
    int tid = threadIdx.x, lane = tid & 63, wave = tid >> 6;
    int wm = wave >> 1, wn = wave & 1;
    int bm = blockIdx.y * 128, bn = blockIdx.x * 128;
    const u16* gA = A + (size_t)(bm + (lane >> 2)) * K + (lane & 3) * 8;
    const u16* gB = BT + (size_t)(bn + (lane >> 2)) * K + (lane & 3) * 8;
    #pragma unroll
    for (int t = 0; t < 2; ++t) {
        int seg = wave * 2 + t;
        gll16(gA + (size_t)seg * 16 * K, &As[0][seg * 512]);
        gll16(gB + (size_t)seg * 16 * K, &Bs[0][seg * 512]);
    }
    f32x4 acc[4][4];
    #pragma unroll
    for (int i = 0; i < 4; ++i)
        #pragma unroll
        for (int j = 0; j < 4; ++j)
            acc[i][j] = (f32x4){0.f, 0.f, 0.f, 0.f};
    int fr = lane & 15, quad = lane >> 4;
    int nit = K >> 5;
    __syncthreads();
    for (int it = 0; it < nit; ++it) {
        int buf = it & 1;
        if (it + 1 < nit) {
            int k0 = (it + 1) * 32;
            #pragma unroll
            for (int t = 0; t < 2; ++t) {
                int seg = wave * 2 + t;
                gll16(gA + k0 + (size_t)seg * 16 * K, &As[buf ^ 1][seg * 512]);
                gll16(gB + k0 + (size_t)seg * 16 * K, &Bs[buf ^ 1][seg * 512]);
            }
        }
        bf16x8 af[4], bfr[4];
        #pragma unroll
        for (int i = 0; i < 4; ++i)
            af[i] = *reinterpret_cast<const bf16x8*>(&As[buf][(wm * 64 + i * 16 + fr) * 32 + quad * 8]);
        #pragma unroll
        for (int j = 0; j < 4; ++j)
            bfr[j] = *reinterpret_cast<const bf16x8*>(&Bs[buf][(wn * 64 + j * 16 + fr) * 32 + quad * 8]);
        #pragma unroll
        for (int i = 0; i < 4; ++i)
            #pragma unroll
            for (int j = 0; j < 4; ++j)
                acc[i][j] = __builtin_amdgcn_mfma_f32_16x16x32_bf16(af[i], bfr[j], acc[i][j], 0, 0, 0);
        __syncthreads();
    }
    int crow0 = bm + wm * 64 + quad * 4;
    int ccol0 = bn + wn * 64 + fr;
    #pragma unroll
    for (int i = 0; i < 4; ++i) {
        #pragma unroll
        for (int r = 0; r < 4; ++r) {
            int m = crow0 + i * 16 + r;
            float vm = valid ? ((valid[m] >= 0) ? 1.0f : 0.0f) : 1.0f;
            #pragma unroll
            for (int j = 0; j < 4; ++j) {
                int n = ccol0 + j * 16;
                float v = acc[i][j][r];
                if (bias) v += bias[n];
                if (act == 1) v = v > 0.f ? v : 0.f;
                else if (act == 2) v = 0.5f * v * (1.0f + erff(v * 0.70710678118654752f));
                v *= vm;
                if (resid) v += resid[(size_t)m * N + n];
                if (c_is_bf16) ((u16*)Cout)[(size_t)m * N + n] = f2us(v);
                else ((float*)Cout)[(size_t)m * N + n] = v;
            }
        }
    }
}

// ---------------------------------------------------------------------------
// Row LayerNorm: 4 rows/block (one per wave), reads f32 x, writes bf16.
__global__ __launch_bounds__(256) void k_ln(
    const float* __restrict__ X, u16* __restrict__ Out,
    const float* __restrict__ g, const float* __restrict__ b)
{
    int row = blockIdx.x * 4 + (threadIdx.x >> 6);
    int lane = threadIdx.x & 63;
    float4 xv = *reinterpret_cast<const float4*>(X + (size_t)row * HDIM + lane * 4);
    float s = xv.x + xv.y + xv.z + xv.w;
    #pragma unroll
    for (int off = 32; off > 0; off >>= 1) s += __shfl_xor(s, off);
    float mu = s * (1.0f / HDIM);
    float d0 = xv.x - mu, d1 = xv.y - mu, d2 = xv.z - mu, d3 = xv.w - mu;
    float sq = d0 * d0 + d1 * d1 + d2 * d2 + d3 * d3;
    #pragma unroll
    for (int off = 32; off > 0; off >>= 1) sq += __shfl_xor(sq, off);
    float rs = rsqrtf(sq * (1.0f / HDIM) + 1e-5f);
    int c = lane * 4;
    float4 gv = *reinterpret_cast<const float4*>(g + c);
    float4 bv = *reinterpret_cast<const float4*>(b + c);
    ushort4 o = { f2us(d0 * rs * gv.x + bv.x), f2us(d1 * rs * gv.y + bv.y),
                  f2us(d2 * rs * gv.z + bv.z), f2us(d3 * rs * gv.w + bv.w) };
    *reinterpret_cast<ushort4*>(Out + (size_t)row * HDIM + c) = o;
}

// ---------------------------------------------------------------------------
// Overlap bias via 512-bit LDS bitmaps (node ids < 500).
__global__ __launch_bounds__(1024) void k_bias(
    const int* __restrict__ nodes, const float* __restrict__ lp,
    const float* __restrict__ ovl_emb, const float* __restrict__ alpha_p,
    float* __restrict__ bias)
{
    int b = blockIdx.x, tid = threadIdx.x;   // 1024 threads
    __shared__ int nd[32][32];
    __shared__ unsigned int bmv[32][17];
    __shared__ float lpc[32];
    __shared__ float emb[16];
    nd[tid >> 5][tid & 31] = nodes[b * 1024 + tid];
    if (tid < 512) bmv[tid >> 4][tid & 15] = 0u;
    if (tid < 32) {
        float l = finite_or_zero(lp[b * 32 + tid]);
        l = l < -30.f ? -30.f : (l > 0.f ? 0.f : l);
        lpc[tid] = l;
    }
    if (tid >= 64 && tid < 64 + KMAXC + 1) emb[tid - 64] = ovl_emb[tid - 64];
    __syncthreads();
    int own = nd[tid >> 5][tid & 31];
    if (own >= 0) atomicOr(&bmv[tid >> 5][own >> 5], 1u << (own & 31));
    __syncthreads();
    int i = tid >> 5, j = tid & 31;
    float alpha = alpha_p[0];
    int cnt = 0;
    #pragma unroll
    for (int k = 0; k < 32; ++k) {
        int nk = nd[i][k];
        if (nk >= 0) cnt += (int)((bmv[j][nk >> 5] >> (nk & 31)) & 1u);
    }
    bias[b * 1024 + tid] = emb[cnt > KMAXC ? KMAXC : cnt] - alpha * lpc[j];
}

// ---------------------------------------------------------------------------
__global__ __launch_bounds__(256) void k_gather(const u16* __restrict__ h, float* __restrict__ x)
{
    int s = blockIdx.x, c = threadIdx.x;
    x[(size_t)s * HDIM + c] = us2f(h[(size_t)s * KNODE * HDIM + c]);
}

// ---------------------------------------------------------------------------
// Attention for one (batch b, head hh): 32x32 scores with bias, softmax, PV.
__global__ __launch_bounds__(256) void k_attn(
    const u16* __restrict__ qkv, const float* __restrict__ bias, u16* __restrict__ o)
{
    int b = blockIdx.x >> 2, hh = blockIdx.x & 3;
    __shared__ float qs[32][65], ks[32][65], vs[32][65];
    __shared__ float sc[32][33];
    int tid = threadIdx.x;
    #pragma unroll
    for (int u = 0; u < 8; ++u) {
        int idx = tid + u * 256;
        int i = idx >> 6, d = idx & 63;
        size_t base = (size_t)(b * 32 + i) * 768;
        qs[i][d] = us2f(qkv[base + hh * 64 + d]);
        ks[i][d] = us2f(qkv[base + 256 + hh * 64 + d]);
        vs[i][d] = us2f(qkv[base + 512 + hh * 64 + d]);
    }
    __syncthreads();
    #pragma unroll
    for (int u = 0; u < 4; ++u) {
        int p = tid + u * 256;
        int i = p >> 5, j = p & 31;
        float s = 0.f;
        #pragma unroll
        for (int d = 0; d < 64; ++d) s += qs[i][d] * ks[j][d];
        sc[i][j] = s * 0.125f + bias[b * 1024 + i * 32 + j];
    }
    __syncthreads();
    if (tid < 32) {
        int i = tid;
        float m = -1e30f;
        for (int j = 0; j < 32; ++j) m = fmaxf(m, sc[i][j]);
        float sum = 0.f;
        for (int j = 0; j < 32; ++j) { float e = expf(sc[i][j] - m); sc[i][j] = e; sum += e; }
        float inv = 1.0f / sum;
        for (int j = 0; j < 32; ++j) sc[i][j] *= inv;
    }
    __syncthreads();
    #pragma unroll
    for (int u = 0; u < 8; ++u) {
        int idx = tid + u * 256;
        int i = idx >> 6, d = idx & 63;
        float a = 0.f;
        #pragma unroll
        for (int j = 0; j < 32; ++j) a += sc[i][j] * vs[j][d];
        o[(size_t)(b * 32 + i) * HDIM + hh * 64 + d] = f2us(a);
    }
}

// ---------------------------------------------------------------------------
// out[b] = sum_i softmax(-lp_c)[i] * xln[b,i,:]  (f32 output)
__global__ __launch_bounds__(256) void k_final(
    const u16* __restrict__ xln, const float* __restrict__ lp, float* __restrict__ out)
{
    int b = blockIdx.x, tid = threadIdx.x;
    __shared__ float w[32];
    if (tid < 32) {
        float l = finite_or_zero(lp[b * 32 + tid]);
        l = l < -30.f ? -30.f : (l > 0.f ? 0.f : l);
        w[tid] = -l;
    }
    __syncthreads();
    if (tid == 0) {
        float m = -1e30f;
        for (int i = 0; i < 32; ++i) m = fmaxf(m, w[i]);
        float s = 0.f;
        for (int i = 0; i < 32; ++i) { float e = expf(w[i] - m); w[i] = e; s += e; }
        float inv = 1.0f / s;
        for (int i = 0; i < 32; ++i) w[i] *= inv;
    }
    __syncthreads();
    float acc = 0.f;
    for (int i = 0; i < 32; ++i) acc += w[i] * us2f(xln[(size_t)(b * 32 + i) * HDIM + tid]);
    out[b * HDIM + tid] = acc;
}

// ---------------------------------------------------------------------------
extern "C" void kernel_launch(void* const* d_in, const int* in_sizes, int n_in,
                              void* d_out, int out_size, void* d_ws, size_t ws_size,
                              hipStream_t stream)
{
    const int*   x_ids    = (const int*)d_in[0];
    const int*   edge_ids = (const int*)d_in[1];
    const int*   srcp     = (const int*)d_in[2];
    const int*   dstp     = (const int*)d_in[3];
    const int*   nodes    = (const int*)d_in[4];
    const int*   dist     = (const int*)d_in[5];
    const float* lp       = (const float*)d_in[6];
    const float* atom_emb = (const float*)d_in[7];
    const float* bond_emb = (const float*)d_in[8];
    const float* dist_emb = (const float*)d_in[9];
    const float* logp_W   = (const float*)d_in[10];
    const float* logp_b   = (const float*)d_in[11];
    const float* gnn_eps  = (const float*)d_in[12];
    const float* gnn_W1   = (const float*)d_in[13];
    const float* gnn_b1   = (const float*)d_in[14];
    const float* gnn_W2   = (const float*)d_in[15];
    const float* gnn_b2   = (const float*)d_in[16];
    const float* ln1_g    = (const float*)d_in[17];
    const float* ln1_b    = (const float*)d_in[18];
    const float* qkv_W    = (const float*)d_in[19];
    const float* out_W    = (const float*)d_in[20];
    const float* out_b    = (const float*)d_in[21];
    const float* ln2_g    = (const float*)d_in[22];
    const float* ln2_b    = (const float*)d_in[23];
    const float* f1_W     = (const float*)d_in[24];
    const float* f1_b     = (const float*)d_in[25];
    const float* f2_W     = (const float*)d_in[26];
    const float* f2_b     = (const float*)d_in[27];
    const float* lnout_g  = (const float*)d_in[28];
    const float* lnout_b  = (const float*)d_in[29];
    const float* ovl_emb  = (const float*)d_in[30];
    const float* alpha    = (const float*)d_in[31];

    // Workspace layout:
    //   [0,32M)    h   bf16 NNODE*H
    //   [32,64M)   z   bf16 (GNN); transformer scratch + WT alias after GNN
    //   [64,96M)   zr  bf16 (GNN); x (f32) aliases start in transformer phase
    //   [96M,97M)  gnn weight transposes (1 MB; ws >= ~99 MB per round-0 run)
    char* ws = (char*)d_ws;
    u16*   h     = (u16*)(ws);
    u16*   z     = (u16*)(ws + 33554432ull);
    u16*   zr    = (u16*)(ws + 67108864ull);
    u16*   gW1T  = (u16*)(ws + 100663296ull);                // 512 KB
    u16*   gW2T  = (u16*)(ws + 100663296ull + 524288ull);    // 512 KB
    // transformer phase (z/zr regions are dead):
    u16*   r     = (u16*)(ws + 33554432ull);                 // 1 MB
    u16*   ob    = (u16*)(ws + 33554432ull + 1048576ull);    // 1 MB
    u16*   qkvb  = (u16*)(ws + 33554432ull + 2097152ull);    // 3 MB
    u16*   ffh   = (u16*)(ws + 33554432ull + 5242880ull);    // 4 MB
    u16*   xln   = (u16*)(ws + 33554432ull + 9437184ull);    // 1 MB
    float* biasb = (float*)(ws + 33554432ull + 10485760ull); // 256 KB
    u16*   qkvT  = (u16*)(ws + 33554432ull + 11534336ull);   // 1.5 MB
    u16*   outT  = (u16*)(ws + 33554432ull + 13107200ull);   // 512 KB
    u16*   f1T   = (u16*)(ws + 33554432ull + 13631488ull);   // 2 MB
    u16*   f2T   = (u16*)(ws + 33554432ull + 15728640ull);   // 2 MB (ends 49.25M)
    float* x     = (float*)(ws + 67108864ull);               // 2 MB f32

    // GNN weight transposes (targets outside live GNN buffers)
    k_wtrans<<<dim3(8, 8, 4), 256, 0, stream>>>(gnn_W1, gW1T, 256, 256);
    k_wtrans<<<dim3(8, 8, 4), 256, 0, stream>>>(gnn_W2, gW2T, 256, 256);

    k_init_h<<<NNODE / 4, 256, 0, stream>>>(x_ids, dist, nodes, lp, atom_emb, dist_emb,
                                            logp_W, logp_b, h);
    for (int l = 0; l < LLAY; ++l) {
        k_edge_z<<<SSUB, 128, 0, stream>>>(h, srcp, dstp, edge_ids, bond_emb, gnn_eps, l, z);
        k_tgemm<<<dim3(2, NNODE / 128), 256, 0, stream>>>(
            z, gW1T + l * 65536, gnn_b1 + l * HDIM, zr, 1,
            nullptr, nullptr, NNODE, 256, HDIM, 1);
        k_tgemm<<<dim3(2, NNODE / 128), 256, 0, stream>>>(
            zr, gW2T + l * 65536, gnn_b2 + l * HDIM, h, 1,
            nullptr, nodes, NNODE, 256, HDIM, 0);
    }
    // transformer weight transposes (z region dead now)
    k_wtrans<<<dim3(8, 24, 4), 256, 0, stream>>>(qkv_W, qkvT, 256, 768);
    k_wtrans<<<dim3(8, 8, 4), 256, 0, stream>>>(out_W, outT, 256, 256);
    k_wtrans<<<dim3(8, 32, 4), 256, 0, stream>>>(f1_W, f1T, 256, 1024);
    k_wtrans<<<dim3(32, 8, 4), 256, 0, stream>>>(f2_W, f2T, 1024, 256);

    k_bias<<<BATCH, 1024, 0, stream>>>(nodes, lp, ovl_emb, alpha, biasb);
    k_gather<<<SSUB, 256, 0, stream>>>(h, x);
    for (int t = 0; t < TLAY; ++t) {
        k_ln<<<SSUB / 4, 256, 0, stream>>>(x, r, ln1_g + t * HDIM, ln1_b + t * HDIM);
        k_tgemm<<<dim3(6, SSUB / 128), 256, 0, stream>>>(
            r, qkvT + t * 768 * 256, nullptr, qkvb, 1,
            nullptr, nullptr, SSUB, 256, 768, 0);
        k_attn<<<BATCH * NHEAD, 256, 0, stream>>>(qkvb, biasb, ob);
        k_tgemm<<<dim3(2, SSUB / 128), 256, 0, stream>>>(
            ob, outT + t * 65536, out_b + t * HDIM, x, 0,
            x, nullptr, SSUB, 256, HDIM, 0);
        k_ln<<<SSUB / 4, 256, 0, stream>>>(x, r, ln2_g + t * HDIM, ln2_b + t * HDIM);
        k_tgemm<<<dim3(8, SSUB / 128), 256, 0, stream>>>(
            r, f1T + t * 1024 * 256, f1_b + t * 1024, ffh, 1,
            nullptr, nullptr, SSUB, 256, 1024, 2);
        k_tgemm<<<dim3(2, SSUB / 128), 256, 0, stream>>>(
            ffh, f2T + t * 256 * 1024, f2_b + t * HDIM, x, 0,
            x, nullptr, SSUB, 1024, HDIM, 0);
    }
    k_ln<<<SSUB / 4, 256, 0, stream>>>(x, xln, lnout_g, lnout_b);
    k_final<<<BATCH, 256, 0, stream>>>(xln, lp, (float*)d_out);
}

// Round 6
// 958.721 us; speedup vs baseline: 1.3950x; 1.2121x over previous
//
#include <hip/hip_runtime.h>
#include <hip/hip_bf16.h>
#include <math.h>

// Sizes from the reference
#define HDIM   256
#define NHEAD  4
#define LLAY   4
#define TLAY   4
#define KMAXC  10
#define MAXD   32
#define BATCH  64
#define MSUB   32
#define KNODE  32
#define SSUB   2048     // BATCH*MSUB
#define NNODE  65536    // SSUB*KNODE
#define NEDGE  131072
#define EPSPER 64       // NEDGE/SSUB
#define EDN    5

typedef unsigned short u16;   // raw bf16 bits (internal staging only)
typedef __attribute__((ext_vector_type(8))) short bf16x8;
typedef __attribute__((ext_vector_type(4))) float f32x4;

__device__ __forceinline__ float us2f(u16 u) {
    union { unsigned int i; float f; } x; x.i = ((unsigned int)u) << 16; return x.f;
}
__device__ __forceinline__ u16 f2us(float v) {
    union { float f; unsigned int i; } x; x.f = v;
    unsigned int u = x.i;
    u += 0x7fffu + ((u >> 16) & 1u);   // RNE
    return (u16)(u >> 16);
}
__device__ __forceinline__ float finite_or_zero(float v) {
    return (v == v && fabsf(v) <= 3.0e38f) ? v : 0.0f;
}
// async global->LDS, 16B per lane; lds base wave-uniform, lane deposits at +lane*16
__device__ __forceinline__ void gll16(const u16* g, u16* l) {
    __builtin_amdgcn_global_load_lds(
        (const __attribute__((address_space(1))) unsigned int*)g,
        (__attribute__((address_space(3))) unsigned int*)l, 16, 0, 0);
}

// ---------------------------------------------------------------------------
// Weight transpose+convert: W (K x N f32, slice z) -> WT (N x K bf16).
__global__ __launch_bounds__(256) void k_wtrans(
    const float* __restrict__ W, u16* __restrict__ WT, int K, int N)
{
    __shared__ float til[32][33];
    int k0 = blockIdx.x * 32, n0 = blockIdx.y * 32, s = blockIdx.z;
    const float* Wb = W + (size_t)s * K * N;
    u16* Tb = WT + (size_t)s * N * K;
    int j = threadIdx.x & 31, i0 = threadIdx.x >> 5;
    #pragma unroll
    for (int it = 0; it < 4; ++it) {
        int i = i0 + it * 8;
        til[i][j] = Wb[(size_t)(k0 + i) * N + n0 + j];
    }
    __syncthreads();
    #pragma unroll
    for (int it = 0; it < 4; ++it) {
        int i = i0 + it * 8;
        Tb[(size_t)(n0 + i) * K + k0 + j] = f2us(til[j][i]);
    }
}

// ---------------------------------------------------------------------------
// h init: 4 rows/block, vectorized.
__global__ __launch_bounds__(256) void k_init_h(
    const int* __restrict__ x_ids, const int* __restrict__ dist,
    const int* __restrict__ nodes, const float* __restrict__ lp,
    const float* __restrict__ atom_emb, const float* __restrict__ dist_emb,
    const float* __restrict__ logp_W, const float* __restrict__ logp_b,
    u16* __restrict__ h)
{
    int n = blockIdx.x * 4 + (threadIdx.x >> 6);
    int c = (threadIdx.x & 63) * 4;
    float valid = (nodes[n] >= 0) ? 1.0f : 0.0f;
    float lpv = finite_or_zero(lp[n >> 5]);
    int dc = dist[n]; dc = dc < 0 ? 0 : (dc > MAXD ? MAXD : dc);
    float4 wv = *reinterpret_cast<const float4*>(logp_W + c);
    float4 bv = *reinterpret_cast<const float4*>(logp_b + c);
    float4 av = *reinterpret_cast<const float4*>(atom_emb + x_ids[n] * HDIM + c);
    float4 dv = *reinterpret_cast<const float4*>(dist_emb + dc * HDIM + c);
    float p0 = fmaxf(lpv * wv.x + bv.x, 0.f), p1 = fmaxf(lpv * wv.y + bv.y, 0.f);
    float p2 = fmaxf(lpv * wv.z + bv.z, 0.f), p3 = fmaxf(lpv * wv.w + bv.w, 0.f);
    ushort4 o = { f2us((av.x + dv.x + p0) * valid), f2us((av.y + dv.y + p1) * valid),
                  f2us((av.z + dv.z + p2) * valid), f2us((av.w + dv.w + p3) * valid) };
    *reinterpret_cast<ushort4*>(h + (size_t)n * HDIM + c) = o;
}

// ---------------------------------------------------------------------------
// Fully-fused GNN layer. One block = 4 subgraphs = 128 rows of h, in place.
//   phase E: agg = segsum(relu(h[src]+bond)); z = (1+eps)h+agg   (LDS only)
//   phase 1: zr = relu(z @ W1 + b1)                              (LDS only)
//   phase 2: h  = (zr @ W2 + b2) * valid                         (write back)
// LDS 160 KB: [0,64K) h/z tile (XOR-swizzled rows), [64K,128K) agg f32 / zr,
// [128K,160K) W stream dbuf (bond/edges alias buf0 during phase E).
// Swizzle: element (r,c) at r*512B + ((c>>3 ^ (r&7))*16 + (c&7)*2).
__global__ __launch_bounds__(256) void k_gnn(
    u16* __restrict__ h, const int* __restrict__ src, const int* __restrict__ dst,
    const int* __restrict__ eid, const float* __restrict__ bond_emb,
    const float* __restrict__ eps_arr, int layer,
    const float* __restrict__ b1, const float* __restrict__ b2,
    const u16* __restrict__ W1T, const u16* __restrict__ W2T,
    const int* __restrict__ nodes)
{
    __shared__ __align__(16) unsigned char smem[163840];
    u16*   hz    = (u16*)smem;                       // 64 KB
    float* aggF  = (float*)(smem + 65536);           // 64 KB (then zr)
    u16*   zrb   = (u16*)(smem + 65536);
    u16*   wb    = (u16*)(smem + 131072);            // 2 x 16 KB
    float* bondL = (float*)(smem + 131072);          // 5 KB (aliases wb[0])
    int*   srcL  = (int*)(smem + 131072 + 5120);
    int*   dstL  = srcL + 256;
    int*   eidL  = srcL + 512;

    int tid = threadIdx.x, lane = tid & 63, wave = tid >> 6;
    int row0 = blockIdx.x * 128;
    int fr = lane & 15, quad = lane >> 4;

    // ---- stage h tile (swizzled), W1 chunk0 -> wb[1], edges/bond ----
    #pragma unroll
    for (int t = 0; t < 16; ++t) {
        int v = wave * 16 + t;
        int r = v * 2 + (lane >> 5);
        int g = (lane & 31) ^ (r & 7);
        gll16(h + (size_t)(row0 + r) * 256 + g * 8, (u16*)(smem + v * 1024));
    }
    #pragma unroll
    for (int t = 0; t < 4; ++t) {
        int v = wave * 4 + t;
        int idx = v * 64 + lane;
        int nrow = idx & 255, cp = idx >> 8;
        gll16(W1T + (size_t)nrow * 256 + cp * 8, (u16*)(smem + 131072 + 16384 + v * 1024));
    }
    for (int i = tid; i < EDN * 256; i += 256) bondL[i] = bond_emb[i];
    srcL[tid] = src[blockIdx.x * 256 + tid];
    dstL[tid] = dst[blockIdx.x * 256 + tid];
    eidL[tid] = eid[blockIdx.x * 256 + tid];
    float ep1 = 1.0f + eps_arr[layer];
    __syncthreads();

    // ---- phase E: two subgraph-pairs, col-ownership => race-free ----
    int sg = tid >> 7, tl = tid & 127, c = tl * 2;
    int ch = c >> 3, cw = c & 7;
    for (int p = 0; p < 2; ++p) {
        float* ag = aggF + (sg * 32) * 256 + c;
        for (int rr = 0; rr < 32; ++rr)
            *reinterpret_cast<float2*>(ag + rr * 256) = (float2){0.f, 0.f};
        int ebase = (p * 2 + sg) * 64;
        for (int e = 0; e < 64; ++e) {
            int ii = ebase + e;
            int sl = srcL[ii] - row0;
            int dl = dstL[ii] - row0 - p * 64;
            int be = eidL[ii];
            unsigned int hv = *reinterpret_cast<const unsigned int*>(
                hz + sl * 256 + ((ch ^ (sl & 7)) * 8) + cw);
            float2 bo = *reinterpret_cast<const float2*>(bondL + be * 256 + c);
            float m0 = us2f((u16)(hv & 0xffff)) + bo.x;
            float m1 = us2f((u16)(hv >> 16)) + bo.y;
            float2* ap = reinterpret_cast<float2*>(aggF + dl * 256 + c);
            float2 av = *ap;
            av.x += m0 > 0.f ? m0 : 0.f;
            av.y += m1 > 0.f ? m1 : 0.f;
            *ap = av;
        }
        int rbase = p * 64 + sg * 32;
        for (int rr = 0; rr < 32; ++rr) {
            int r = rbase + rr;
            unsigned int* zp = reinterpret_cast<unsigned int*>(
                hz + r * 256 + ((ch ^ (r & 7)) * 8) + cw);
            unsigned int hv = *zp;
            float2 av = *reinterpret_cast<const float2*>(aggF + (r - p * 64) * 256 + c);
            float z0 = ep1 * us2f((u16)(hv & 0xffff)) + av.x;
            float z1 = ep1 * us2f((u16)(hv >> 16)) + av.y;
            *zp = ((unsigned int)f2us(z1) << 16) | (unsigned int)f2us(z0);
        }
    }
    __syncthreads();

    // ---- phase 1: D'[n1][m] = W1frag x zfrag ; zr = relu(D'+b1) ----
    f32x4 acc[4][8];
    #pragma unroll
    for (int i = 0; i < 4; ++i)
        #pragma unroll
        for (int j = 0; j < 8; ++j) acc[i][j] = (f32x4){0.f, 0.f, 0.f, 0.f};
    for (int kc = 0; kc < 8; ++kc) {
        int buf = (kc + 1) & 1;
        const u16* WT = (kc < 7) ? W1T : W2T;
        int kn = (kc < 7) ? kc + 1 : 0;
        #pragma unroll
        for (int t = 0; t < 4; ++t) {
            int v = wave * 4 + t;
            int idx = v * 64 + lane;
            int nrow = idx & 255, cp = idx >> 8;
            gll16(WT + (size_t)nrow * 256 + kn * 32 + cp * 8,
                  (u16*)(smem + 131072 + (buf ^ 1) * 16384 + v * 1024));
        }
        bf16x8 af[4], bfv[8];
        #pragma unroll
        for (int i = 0; i < 4; ++i) {
            int n1 = wave * 64 + i * 16 + fr;
            af[i] = *reinterpret_cast<const bf16x8*>(wb + buf * 8192 + quad * 2048 + n1 * 8);
        }
        #pragma unroll
        for (int j = 0; j < 8; ++j) {
            int m = j * 16 + fr;
            bfv[j] = *reinterpret_cast<const bf16x8*>(hz + m * 256 + (((kc * 4 + quad) ^ (m & 7)) * 8));
        }
        #pragma unroll
        for (int i = 0; i < 4; ++i)
            #pragma unroll
            for (int j = 0; j < 8; ++j)
                acc[i][j] = __builtin_amdgcn_mfma_f32_16x16x32_bf16(af[i], bfv[j], acc[i][j], 0, 0, 0);
        __syncthreads();
    }
    #pragma unroll
    for (int i = 0; i < 4; ++i) {
        int n1b = wave * 64 + i * 16 + quad * 4;
        float4 bb = *reinterpret_cast<const float4*>(b1 + n1b);
        #pragma unroll
        for (int j = 0; j < 8; ++j) {
            int m = j * 16 + fr;
            ushort4 o = { f2us(fmaxf(acc[i][j][0] + bb.x, 0.f)),
                          f2us(fmaxf(acc[i][j][1] + bb.y, 0.f)),
                          f2us(fmaxf(acc[i][j][2] + bb.z, 0.f)),
                          f2us(fmaxf(acc[i][j][3] + bb.w, 0.f)) };
            *reinterpret_cast<ushort4*>(zrb + m * 256 + (((n1b >> 3) ^ (m & 7)) * 8) + (n1b & 7)) = o;
        }
    }
    __syncthreads();

    // ---- phase 2: D'[n2][m] = W2frag x zrfrag ; h = (D'+b2)*valid ----
    #pragma unroll
    for (int i = 0; i < 4; ++i)
        #pragma unroll
        for (int j = 0; j < 8; ++j) acc[i][j] = (f32x4){0.f, 0.f, 0.f, 0.f};
    for (int kc = 0; kc < 8; ++kc) {
        int buf = (kc + 1) & 1;
        if (kc < 7) {
            #pragma unroll
            for (int t = 0; t < 4; ++t) {
                int v = wave * 4 + t;
                int idx = v * 64 + lane;
                int nrow = idx & 255, cp = idx >> 8;
                gll16(W2T + (size_t)nrow * 256 + (kc + 1) * 32 + cp * 8,
                      (u16*)(smem + 131072 + (buf ^ 1) * 16384 + v * 1024));
            }
        }
        bf16x8 af[4], bfv[8];
        #pragma unroll
        for (int i = 0; i < 4; ++i) {
            int n2 = wave * 64 + i * 16 + fr;
            af[i] = *reinterpret_cast<const bf16x8*>(wb + buf * 8192 + quad * 2048 + n2 * 8);
        }
        #pragma unroll
        for (int j = 0; j < 8; ++j) {
            int m = j * 16 + fr;
            bfv[j] = *reinterpret_cast<const bf16x8*>(zrb + m * 256 + (((kc * 4 + quad) ^ (m & 7)) * 8));
        }
        #pragma unroll
        for (int i = 0; i < 4; ++i)
            #pragma unroll
            for (int j = 0; j < 8; ++j)
                acc[i][j] = __builtin_amdgcn_mfma_f32_16x16x32_bf16(af[i], bfv[j], acc[i][j], 0, 0, 0);
        __syncthreads();
    }
    #pragma unroll
    for (int i = 0; i < 4; ++i) {
        int n2b = wave * 64 + i * 16 + quad * 4;
        float4 bb = *reinterpret_cast<const float4*>(b2 + n2b);
        #pragma unroll
        for (int j = 0; j < 8; ++j) {
            int m = j * 16 + fr;
            float vm = (nodes[row0 + m] >= 0) ? 1.0f : 0.0f;
            ushort4 o = { f2us((acc[i][j][0] + bb.x) * vm),
                          f2us((acc[i][j][1] + bb.y) * vm),
                          f2us((acc[i][j][2] + bb.z) * vm),
                          f2us((acc[i][j][3] + bb.w) * vm) };
            *reinterpret_cast<ushort4*>(hz + m * 256 + (((n2b >> 3) ^ (m & 7)) * 8) + (n2b & 7)) = o;
        }
    }
    __syncthreads();

    // ---- write back 64 KB, coalesced ----
    for (int it = 0; it < 16; ++it) {
        int t16 = it * 256 + tid;          // 16B chunk id, 4096 total
        int r = t16 >> 5, g = t16 & 31;
        *reinterpret_cast<uint4*>(h + (size_t)(row0 + r) * 256 + g * 8) =
            *reinterpret_cast<const uint4*>(hz + r * 256 + ((g ^ (r & 7)) * 8));
    }
}

// ---------------------------------------------------------------------------
// Pure-bf16 MFMA GEMM (transformer): C = epi(A @ BT^T + bias).
__global__ __launch_bounds__(256) void k_tgemm(
    const u16* __restrict__ A, const u16* __restrict__ BT,
    const float* __restrict__ bias, void* __restrict__ Cout, int c_is_bf16,
    const float* __restrict__ resid, const int* __restrict__ valid,
    int M, int K, int N, int act)
{
    __shared__ __align__(16) u16 As[2][128 * 32];
    __shared__ __align__(16) u16 Bs[2][128 * 32];
    int tid = threadIdx.x, lane = tid & 63, wave = tid >> 6;
    int wm = wave >> 1, wn = wave & 1;
    int bm = blockIdx.y * 128, bn = blockIdx.x * 128;
    const u16* gA = A + (size_t)(bm + (lane >> 2)) * K + (lane & 3) * 8;
    const u16* gB = BT + (size_t)(bn + (lane >> 2)) * K + (lane & 3) * 8;
    #pragma unroll
    for (int t = 0; t < 2; ++t) {
        int seg = wave * 2 + t;
        gll16(gA + (size_t)seg * 16 * K, &As[0][seg * 512]);
        gll16(gB + (size_t)seg * 16 * K, &Bs[0][seg * 512]);
    }
    f32x4 acc[4][4];
    #pragma unroll
    for (int i = 0; i < 4; ++i)
        #pragma unroll
        for (int j = 0; j < 4; ++j)
            acc[i][j] = (f32x4){0.f, 0.f, 0.f, 0.f};
    int fr = lane & 15, quad = lane >> 4;
    int nit = K >> 5;
    __syncthreads();
    for (int it = 0; it < nit; ++it) {
        int buf = it & 1;
        if (it + 1 < nit) {
            int k0 = (it + 1) * 32;
            #pragma unroll
            for (int t = 0; t < 2; ++t) {
                int seg = wave * 2 + t;
                gll16(gA + k0 + (size_t)seg * 16 * K, &As[buf ^ 1][seg * 512]);
                gll16(gB + k0 + (size_t)seg * 16 * K, &Bs[buf ^ 1][seg * 512]);
            }
        }
        bf16x8 af[4], bfr[4];
        #pragma unroll
        for (int i = 0; i < 4; ++i)
            af[i] = *reinterpret_cast<const bf16x8*>(&As[buf][(wm * 64 + i * 16 + fr) * 32 + quad * 8]);
        #pragma unroll
        for (int j = 0; j < 4; ++j)
            bfr[j] = *reinterpret_cast<const bf16x8*>(&Bs[buf][(wn * 64 + j * 16 + fr) * 32 + quad * 8]);
        #pragma unroll
        for (int i = 0; i < 4; ++i)
            #pragma unroll
            for (int j = 0; j < 4; ++j)
                acc[i][j] = __builtin_amdgcn_mfma_f32_16x16x32_bf16(af[i], bfr[j], acc[i][j], 0, 0, 0);
        __syncthreads();
    }
    int crow0 = bm + wm * 64 + quad * 4;
    int ccol0 = bn + wn * 64 + fr;
    #pragma unroll
    for (int i = 0; i < 4; ++i) {
        #pragma unroll
        for (int r = 0; r < 4; ++r) {
            int m = crow0 + i * 16 + r;
            float vm = valid ? ((valid[m] >= 0) ? 1.0f : 0.0f) : 1.0f;
            #pragma unroll
            for (int j = 0; j < 4; ++j) {
                int n = ccol0 + j * 16;
                float v = acc[i][j][r];
                if (bias) v += bias[n];
                if (act == 1) v = v > 0.f ? v : 0.f;
                else if (act == 2) v = 0.5f * v * (1.0f + erff(v * 0.70710678118654752f));
                v *= vm;
                if (resid) v += resid[(size_t)m * N + n];
                if (c_is_bf16) ((u16*)Cout)[(size_t)m * N + n] = f2us(v);
                else ((float*)Cout)[(size_t)m * N + n] = v;
            }
        }
    }
}

// ---------------------------------------------------------------------------
// Row LayerNorm: 4 rows/block (one per wave), reads f32 x, writes bf16.
__global__ __launch_bounds__(256) void k_ln(
    const float* __restrict__ X, u16* __restrict__ Out,
    const float* __restrict__ g, const float* __restrict__ b)
{
    int row = blockIdx.x * 4 + (threadIdx.x >> 6);
    int lane = threadIdx.x & 63;
    float4 xv = *reinterpret_cast<const float4*>(X + (size_t)row * HDIM + lane * 4);
    float s = xv.x + xv.y + xv.z + xv.w;
    #pragma unroll
    for (int off = 32; off > 0; off >>= 1) s += __shfl_xor(s, off);
    float mu = s * (1.0f / HDIM);
    float d0 = xv.x - mu, d1 = xv.y - mu, d2 = xv.z - mu, d3 = xv.w - mu;
    float sq = d0 * d0 + d1 * d1 + d2 * d2 + d3 * d3;
    #pragma unroll
    for (int off = 32; off > 0; off >>= 1) sq += __shfl_xor(sq, off);
    float rs = rsqrtf(sq * (1.0f / HDIM) + 1e-5f);
    int c = lane * 4;
    float4 gv = *reinterpret_cast<const float4*>(g + c);
    float4 bv = *reinterpret_cast<const float4*>(b + c);
    ushort4 o = { f2us(d0 * rs * gv.x + bv.x), f2us(d1 * rs * gv.y + bv.y),
                  f2us(d2 * rs * gv.z + bv.z), f2us(d3 * rs * gv.w + bv.w) };
    *reinterpret_cast<ushort4*>(Out + (size_t)row * HDIM + c) = o;
}

// ---------------------------------------------------------------------------
// Overlap bias via 512-bit LDS bitmaps (node ids < 500).
__global__ __launch_bounds__(1024) void k_bias(
    const int* __restrict__ nodes, const float* __restrict__ lp,
    const float* __restrict__ ovl_emb, const float* __restrict__ alpha_p,
    float* __restrict__ bias)
{
    int b = blockIdx.x, tid = threadIdx.x;
    __shared__ int nd[32][32];
    __shared__ unsigned int bmv[32][17];
    __shared__ float lpc[32];
    __shared__ float emb[16];
    nd[tid >> 5][tid & 31] = nodes[b * 1024 + tid];
    if (tid < 512) bmv[tid >> 4][tid & 15] = 0u;
    if (tid < 32) {
        float l = finite_or_zero(lp[b * 32 + tid]);
        l = l < -30.f ? -30.f : (l > 0.f ? 0.f : l);
        lpc[tid] = l;
    }
    if (tid >= 64 && tid < 64 + KMAXC + 1) emb[tid - 64] = ovl_emb[tid - 64];
    __syncthreads();
    int own = nd[tid >> 5][tid & 31];
    if (own >= 0) atomicOr(&bmv[tid >> 5][own >> 5], 1u << (own & 31));
    __syncthreads();
    int i = tid >> 5, j = tid & 31;
    float alpha = alpha_p[0];
    int cnt = 0;
    #pragma unroll
    for (int k = 0; k < 32; ++k) {
        int nk = nd[i][k];
        if (nk >= 0) cnt += (int)((bmv[j][nk >> 5] >> (nk & 31)) & 1u);
    }
    bias[b * 1024 + tid] = emb[cnt > KMAXC ? KMAXC : cnt] - alpha * lpc[j];
}

// ---------------------------------------------------------------------------
__global__ __launch_bounds__(256) void k_gather(const u16* __restrict__ h, float* __restrict__ x)
{
    int s = blockIdx.x, c = threadIdx.x;
    x[(size_t)s * HDIM + c] = us2f(h[(size_t)s * KNODE * HDIM + c]);
}

// ---------------------------------------------------------------------------
// Attention for one (batch b, head hh): 32x32 scores with bias, softmax, PV.
__global__ __launch_bounds__(256) void k_attn(
    const u16* __restrict__ qkv, const float* __restrict__ bias, u16* __restrict__ o)
{
    int b = blockIdx.x >> 2, hh = blockIdx.x & 3;
    __shared__ float qs[32][65], ks[32][65], vs[32][65];
    __shared__ float sc[32][33];
    int tid = threadIdx.x;
    #pragma unroll
    for (int u = 0; u < 8; ++u) {
        int idx = tid + u * 256;
        int i = idx >> 6, d = idx & 63;
        size_t base = (size_t)(b * 32 + i) * 768;
        qs[i][d] = us2f(qkv[base + hh * 64 + d]);
        ks[i][d] = us2f(qkv[base + 256 + hh * 64 + d]);
        vs[i][d] = us2f(qkv[base + 512 + hh * 64 + d]);
    }
    __syncthreads();
    #pragma unroll
    for (int u = 0; u < 4; ++u) {
        int p = tid + u * 256;
        int i = p >> 5, j = p & 31;
        float s = 0.f;
        #pragma unroll
        for (int d = 0; d < 64; ++d) s += qs[i][d] * ks[j][d];
        sc[i][j] = s * 0.125f + bias[b * 1024 + i * 32 + j];
    }
    __syncthreads();
    if (tid < 32) {
        int i = tid;
        float m = -1e30f;
        for (int j = 0; j < 32; ++j) m = fmaxf(m, sc[i][j]);
        float sum = 0.f;
        for (int j = 0; j < 32; ++j) { float e = expf(sc[i][j] - m); sc[i][j] = e; sum += e; }
        float inv = 1.0f / sum;
        for (int j = 0; j < 32; ++j) sc[i][j] *= inv;
    }
    __syncthreads();
    #pragma unroll
    for (int u = 0; u < 8; ++u) {
        int idx = tid + u * 256;
        int i = idx >> 6, d = idx & 63;
        float a = 0.f;
        #pragma unroll
        for (int j = 0; j < 32; ++j) a += sc[i][j] * vs[j][d];
        o[(size_t)(b * 32 + i) * HDIM + hh * 64 + d] = f2us(a);
    }
}

// ---------------------------------------------------------------------------
// out[b] = sum_i softmax(-lp_c)[i] * xln[b,i,:]  (f32 output)
__global__ __launch_bounds__(256) void k_final(
    const u16* __restrict__ xln, const float* __restrict__ lp, float* __restrict__ out)
{
    int b = blockIdx.x, tid = threadIdx.x;
    __shared__ float w[32];
    if (tid < 32) {
        float l = finite_or_zero(lp[b * 32 + tid]);
        l = l < -30.f ? -30.f : (l > 0.f ? 0.f : l);
        w[tid] = -l;
    }
    __syncthreads();
    if (tid == 0) {
        float m = -1e30f;
        for (int i = 0; i < 32; ++i) m = fmaxf(m, w[i]);
        float s = 0.f;
        for (int i = 0; i < 32; ++i) { float e = expf(w[i] - m); w[i] = e; s += e; }
        float inv = 1.0f / s;
        for (int i = 0; i < 32; ++i) w[i] *= inv;
    }
    __syncthreads();
    float acc = 0.f;
    for (int i = 0; i < 32; ++i) acc += w[i] * us2f(xln[(size_t)(b * 32 + i) * HDIM + tid]);
    out[b * HDIM + tid] = acc;
}

// ---------------------------------------------------------------------------
extern "C" void kernel_launch(void* const* d_in, const int* in_sizes, int n_in,
                              void* d_out, int out_size, void* d_ws, size_t ws_size,
                              hipStream_t stream)
{
    const int*   x_ids    = (const int*)d_in[0];
    const int*   edge_ids = (const int*)d_in[1];
    const int*   srcp     = (const int*)d_in[2];
    const int*   dstp     = (const int*)d_in[3];
    const int*   nodes    = (const int*)d_in[4];
    const int*   dist     = (const int*)d_in[5];
    const float* lp       = (const float*)d_in[6];
    const float* atom_emb = (const float*)d_in[7];
    const float* bond_emb = (const float*)d_in[8];
    const float* dist_emb = (const float*)d_in[9];
    const float* logp_W   = (const float*)d_in[10];
    const float* logp_b   = (const float*)d_in[11];
    const float* gnn_eps  = (const float*)d_in[12];
    const float* gnn_W1   = (const float*)d_in[13];
    const float* gnn_b1   = (const float*)d_in[14];
    const float* gnn_W2   = (const float*)d_in[15];
    const float* gnn_b2   = (const float*)d_in[16];
    const float* ln1_g    = (const float*)d_in[17];
    const float* ln1_b    = (const float*)d_in[18];
    const float* qkv_W    = (const float*)d_in[19];
    const float* out_W    = (const float*)d_in[20];
    const float* out_b    = (const float*)d_in[21];
    const float* ln2_g    = (const float*)d_in[22];
    const float* ln2_b    = (const float*)d_in[23];
    const float* f1_W     = (const float*)d_in[24];
    const float* f1_b     = (const float*)d_in[25];
    const float* f2_W     = (const float*)d_in[26];
    const float* f2_b     = (const float*)d_in[27];
    const float* lnout_g  = (const float*)d_in[28];
    const float* lnout_b  = (const float*)d_in[29];
    const float* ovl_emb  = (const float*)d_in[30];
    const float* alpha    = (const float*)d_in[31];

    char* ws = (char*)d_ws;
    u16*   h     = (u16*)(ws);
    u16*   gW1T  = (u16*)(ws + 100663296ull);                // 512 KB
    u16*   gW2T  = (u16*)(ws + 100663296ull + 524288ull);    // 512 KB
    // transformer scratch (z region, dead during GNN):
    u16*   r     = (u16*)(ws + 33554432ull);                 // 1 MB
    u16*   ob    = (u16*)(ws + 33554432ull + 1048576ull);    // 1 MB
    u16*   qkvb  = (u16*)(ws + 33554432ull + 2097152ull);    // 3 MB
    u16*   ffh   = (u16*)(ws + 33554432ull + 5242880ull);    // 4 MB
    u16*   xln   = (u16*)(ws + 33554432ull + 9437184ull);    // 1 MB
    float* biasb = (float*)(ws + 33554432ull + 10485760ull); // 256 KB
    u16*   qkvT  = (u16*)(ws + 33554432ull + 11534336ull);   // 1.5 MB
    u16*   outT  = (u16*)(ws + 33554432ull + 13107200ull);   // 512 KB
    u16*   f1T   = (u16*)(ws + 33554432ull + 13631488ull);   // 2 MB
    u16*   f2T   = (u16*)(ws + 33554432ull + 15728640ull);   // 2 MB
    float* x     = (float*)(ws + 67108864ull);               // 2 MB f32

    k_wtrans<<<dim3(8, 8, 4), 256, 0, stream>>>(gnn_W1, gW1T, 256, 256);
    k_wtrans<<<dim3(8, 8, 4), 256, 0, stream>>>(gnn_W2, gW2T, 256, 256);
    k_init_h<<<NNODE / 4, 256, 0, stream>>>(x_ids, dist, nodes, lp, atom_emb, dist_emb,
                                            logp_W, logp_b, h);
    for (int l = 0; l < LLAY; ++l) {
        k_gnn<<<NNODE / 128, 256, 0, stream>>>(
            h, srcp, dstp, edge_ids, bond_emb, gnn_eps, l,
            gnn_b1 + l * HDIM, gnn_b2 + l * HDIM,
            gW1T + l * 65536, gW2T + l * 65536, nodes);
    }
    k_wtrans<<<dim3(8, 24, 4), 256, 0, stream>>>(qkv_W, qkvT, 256, 768);
    k_wtrans<<<dim3(8, 8, 4), 256, 0, stream>>>(out_W, outT, 256, 256);
    k_wtrans<<<dim3(8, 32, 4), 256, 0, stream>>>(f1_W, f1T, 256, 1024);
    k_wtrans<<<dim3(32, 8, 4), 256, 0, stream>>>(f2_W, f2T, 1024, 256);
    k_bias<<<BATCH, 1024, 0, stream>>>(nodes, lp, ovl_emb, alpha, biasb);
    k_gather<<<SSUB, 256, 0, stream>>>(h, x);
    for (int t = 0; t < TLAY; ++t) {
        k_ln<<<SSUB / 4, 256, 0, stream>>>(x, r, ln1_g + t * HDIM, ln1_b + t * HDIM);
        k_tgemm<<<dim3(6, SSUB / 128), 256, 0, stream>>>(
            r, qkvT + t * 768 * 256, nullptr, qkvb, 1,
            nullptr, nullptr, SSUB, 256, 768, 0);
        k_attn<<<BATCH * NHEAD, 256, 0, stream>>>(qkvb, biasb, ob);
        k_tgemm<<<dim3(2, SSUB / 128), 256, 0, stream>>>(
            ob, outT + t * 65536, out_b + t * HDIM, x, 0,
            x, nullptr, SSUB, 256, HDIM, 0);
        k_ln<<<SSUB / 4, 256, 0, stream>>>(x, r, ln2_g + t * HDIM, ln2_b + t * HDIM);
        k_tgemm<<<dim3(8, SSUB / 128), 256, 0, stream>>>(
            r, f1T + t * 1024 * 256, f1_b + t * 1024, ffh, 1,
            nullptr, nullptr, SSUB, 256, 1024, 2);
        k_tgemm<<<dim3(2, SSUB / 128), 256, 0, stream>>>(
            ffh, f2T + t * 256 * 1024, f2_b + t * HDIM, x, 0,
            x, nullptr, SSUB, 1024, HDIM, 0);
    }
    k_ln<<<SSUB / 4, 256, 0, stream>>>(x, xln, lnout_g, lnout_b);
    k_final<<<BATCH, 256, 0, stream>>>(xln, lp, (float*)d_out);
}

// Round 7
// 678.237 us; speedup vs baseline: 1.9720x; 1.4135x over previous
//
#include <hip/hip_runtime.h>
#include <hip/hip_bf16.h>
#include <math.h>

// Sizes from the reference
#define HDIM   256
#define NHEAD  4
#define LLAY   4
#define TLAY   4
#define KMAXC  10
#define MAXD   32
#define BATCH  64
#define MSUB   32
#define KNODE  32
#define SSUB   2048     // BATCH*MSUB
#define NNODE  65536    // SSUB*KNODE
#define NEDGE  131072
#define EPSPER 64       // NEDGE/SSUB
#define EDN    5

typedef unsigned short u16;   // raw bf16 bits (internal staging only)
typedef __attribute__((ext_vector_type(8))) short bf16x8;
typedef __attribute__((ext_vector_type(4))) float f32x4;

__device__ __forceinline__ float us2f(u16 u) {
    union { unsigned int i; float f; } x; x.i = ((unsigned int)u) << 16; return x.f;
}
__device__ __forceinline__ u16 f2us(float v) {
    union { float f; unsigned int i; } x; x.f = v;
    unsigned int u = x.i;
    u += 0x7fffu + ((u >> 16) & 1u);   // RNE
    return (u16)(u >> 16);
}
__device__ __forceinline__ float finite_or_zero(float v) {
    return (v == v && fabsf(v) <= 3.0e38f) ? v : 0.0f;
}
// async global->LDS, 16B per lane; lds base wave-uniform, lane deposits at +lane*16
__device__ __forceinline__ void gll16(const u16* g, u16* l) {
    __builtin_amdgcn_global_load_lds(
        (const __attribute__((address_space(1))) unsigned int*)g,
        (__attribute__((address_space(3))) unsigned int*)l, 16, 0, 0);
}

// ---------------------------------------------------------------------------
// Weight transpose+convert: W (K x N f32, slice z) -> WT (N x K bf16).
__global__ __launch_bounds__(256) void k_wtrans(
    const float* __restrict__ W, u16* __restrict__ WT, int K, int N)
{
    __shared__ float til[32][33];
    int k0 = blockIdx.x * 32, n0 = blockIdx.y * 32, s = blockIdx.z;
    const float* Wb = W + (size_t)s * K * N;
    u16* Tb = WT + (size_t)s * N * K;
    int j = threadIdx.x & 31, i0 = threadIdx.x >> 5;
    #pragma unroll
    for (int it = 0; it < 4; ++it) {
        int i = i0 + it * 8;
        til[i][j] = Wb[(size_t)(k0 + i) * N + n0 + j];
    }
    __syncthreads();
    #pragma unroll
    for (int it = 0; it < 4; ++it) {
        int i = i0 + it * 8;
        Tb[(size_t)(n0 + i) * K + k0 + j] = f2us(til[j][i]);
    }
}

// ---------------------------------------------------------------------------
// h init: 4 rows/block, vectorized.
__global__ __launch_bounds__(256) void k_init_h(
    const int* __restrict__ x_ids, const int* __restrict__ dist,
    const int* __restrict__ nodes, const float* __restrict__ lp,
    const float* __restrict__ atom_emb, const float* __restrict__ dist_emb,
    const float* __restrict__ logp_W, const float* __restrict__ logp_b,
    u16* __restrict__ h)
{
    int n = blockIdx.x * 4 + (threadIdx.x >> 6);
    int c = (threadIdx.x & 63) * 4;
    float valid = (nodes[n] >= 0) ? 1.0f : 0.0f;
    float lpv = finite_or_zero(lp[n >> 5]);
    int dc = dist[n]; dc = dc < 0 ? 0 : (dc > MAXD ? MAXD : dc);
    float4 wv = *reinterpret_cast<const float4*>(logp_W + c);
    float4 bv = *reinterpret_cast<const float4*>(logp_b + c);
    float4 av = *reinterpret_cast<const float4*>(atom_emb + x_ids[n] * HDIM + c);
    float4 dv = *reinterpret_cast<const float4*>(dist_emb + dc * HDIM + c);
    float p0 = fmaxf(lpv * wv.x + bv.x, 0.f), p1 = fmaxf(lpv * wv.y + bv.y, 0.f);
    float p2 = fmaxf(lpv * wv.z + bv.z, 0.f), p3 = fmaxf(lpv * wv.w + bv.w, 0.f);
    ushort4 o = { f2us((av.x + dv.x + p0) * valid), f2us((av.y + dv.y + p1) * valid),
                  f2us((av.z + dv.z + p2) * valid), f2us((av.w + dv.w + p3) * valid) };
    *reinterpret_cast<ushort4*>(h + (size_t)n * HDIM + c) = o;
}

// ---------------------------------------------------------------------------
// Fused GNN layer v2: one block = 2 subgraphs = 64 rows, in place.
// LDS 72 KB (2 blocks/CU): [0,32K) hz (swizzled), [32K,64K) agg f32 / zr bf16,
// [64K,72K) bond + edge lists. Weights live in REGISTERS (wf[4][8] = 128 VGPR
// per wave = that wave's full 64xK slice), loaded straight from L2 -> no
// weight streaming, no K-loop barriers.
// Swizzle: elem (r,c) at r*512B + (((c>>3) ^ (r&7))*16 + (c&7)*2).
__global__ __launch_bounds__(256, 2) void k_gnn(
    u16* __restrict__ h, const int* __restrict__ src, const int* __restrict__ dst,
    const int* __restrict__ eid, const float* __restrict__ bond_emb,
    const float* __restrict__ eps_arr, int layer,
    const float* __restrict__ b1, const float* __restrict__ b2,
    const u16* __restrict__ W1T, const u16* __restrict__ W2T,
    const int* __restrict__ nodes)
{
    __shared__ __align__(16) unsigned char smem[73728];
    u16*   hz    = (u16*)smem;                       // 32 KB
    float* aggF  = (float*)(smem + 32768);           // 32 KB (agg, then zr)
    u16*   zrb   = (u16*)(smem + 32768);
    float* bondL = (float*)(smem + 65536);           // 5 KB
    int*   srcL  = (int*)(smem + 65536 + 5120);      // 128 x3
    int*   dstL  = srcL + 128;
    int*   eidL  = srcL + 256;

    int tid = threadIdx.x, lane = tid & 63, wave = tid >> 6;
    int row0 = blockIdx.x * 64;
    int fr = lane & 15, quad = lane >> 4;

    // ---- stage hz (swizzled) + bond + edge lists ----
    #pragma unroll
    for (int t = 0; t < 8; ++t) {
        int v = wave * 8 + t;               // 1KB segment = 2 rows
        int r = v * 2 + (lane >> 5);
        int g = (lane & 31) ^ (r & 7);
        gll16(h + (size_t)(row0 + r) * 256 + g * 8, (u16*)(smem + v * 1024));
    }
    for (int i = tid; i < EDN * 256; i += 256) bondL[i] = bond_emb[i];
    if (tid < 128) {
        srcL[tid] = src[blockIdx.x * 128 + tid];
        dstL[tid] = dst[blockIdx.x * 128 + tid];
        eidL[tid] = eid[blockIdx.x * 128 + tid];
    }
    float ep1 = 1.0f + eps_arr[layer];
    __syncthreads();

    // ---- phase E: one subgraph at a time, all 256 threads, 1 col each ----
    int c = tid, ch = c >> 3, cl = c & 7;
    for (int p = 0; p < 2; ++p) {
        if (p) __syncthreads();             // agg reuse
        for (int r = 0; r < 32; ++r) aggF[r * 256 + c] = 0.f;
        #pragma unroll 4
        for (int e = 0; e < 64; ++e) {
            int ii = p * 64 + e;
            int sl = srcL[ii] - row0;
            int dl = dstL[ii] - row0 - p * 32;
            int be = eidL[ii];
            float m = us2f(hz[sl * 256 + ((ch ^ (sl & 7)) * 8) + cl]) + bondL[be * 256 + c];
            aggF[dl * 256 + c] += m > 0.f ? m : 0.f;
        }
        for (int r = 0; r < 32; ++r) {
            int row = p * 32 + r;
            int idx = row * 256 + ((ch ^ (row & 7)) * 8) + cl;
            hz[idx] = f2us(ep1 * us2f(hz[idx]) + aggF[r * 256 + c]);
        }
    }
    __syncthreads();

    // ---- phase 1: zr = relu(z @ W1 + b1); D'[n1][m] = W1frag x zfrag ----
    bf16x8 wf[4][8];
    #pragma unroll
    for (int i = 0; i < 4; ++i)
        #pragma unroll
        for (int kc = 0; kc < 8; ++kc)
            wf[i][kc] = *reinterpret_cast<const bf16x8*>(
                W1T + (size_t)(wave * 64 + i * 16 + fr) * 256 + kc * 32 + quad * 8);
    f32x4 acc[4][4];
    #pragma unroll
    for (int i = 0; i < 4; ++i)
        #pragma unroll
        for (int j = 0; j < 4; ++j) acc[i][j] = (f32x4){0.f, 0.f, 0.f, 0.f};
    #pragma unroll
    for (int kc = 0; kc < 8; ++kc) {
        bf16x8 bfv[4];
        #pragma unroll
        for (int j = 0; j < 4; ++j) {
            int m = j * 16 + fr;
            bfv[j] = *reinterpret_cast<const bf16x8*>(hz + m * 256 + (((kc * 4 + quad) ^ (m & 7)) * 8));
        }
        #pragma unroll
        for (int i = 0; i < 4; ++i)
            #pragma unroll
            for (int j = 0; j < 4; ++j)
                acc[i][j] = __builtin_amdgcn_mfma_f32_16x16x32_bf16(wf[i][kc], bfv[j], acc[i][j], 0, 0, 0);
    }
    __syncthreads();   // aggF fully consumed by all waves before zrb overwrite
    #pragma unroll
    for (int i = 0; i < 4; ++i) {
        int n1b = wave * 64 + i * 16 + quad * 4;
        float4 bb = *reinterpret_cast<const float4*>(b1 + n1b);
        #pragma unroll
        for (int j = 0; j < 4; ++j) {
            int m = j * 16 + fr;
            ushort4 o = { f2us(fmaxf(acc[i][j][0] + bb.x, 0.f)),
                          f2us(fmaxf(acc[i][j][1] + bb.y, 0.f)),
                          f2us(fmaxf(acc[i][j][2] + bb.z, 0.f)),
                          f2us(fmaxf(acc[i][j][3] + bb.w, 0.f)) };
            *reinterpret_cast<ushort4*>(zrb + m * 256 + (((n1b >> 3) ^ (m & 7)) * 8) + (n1b & 7)) = o;
        }
    }
    __syncthreads();

    // ---- phase 2: h = (zr @ W2 + b2) * valid ----
    #pragma unroll
    for (int i = 0; i < 4; ++i)
        #pragma unroll
        for (int kc = 0; kc < 8; ++kc)
            wf[i][kc] = *reinterpret_cast<const bf16x8*>(
                W2T + (size_t)(wave * 64 + i * 16 + fr) * 256 + kc * 32 + quad * 8);
    #pragma unroll
    for (int i = 0; i < 4; ++i)
        #pragma unroll
        for (int j = 0; j < 4; ++j) acc[i][j] = (f32x4){0.f, 0.f, 0.f, 0.f};
    #pragma unroll
    for (int kc = 0; kc < 8; ++kc) {
        bf16x8 bfv[4];
        #pragma unroll
        for (int j = 0; j < 4; ++j) {
            int m = j * 16 + fr;
            bfv[j] = *reinterpret_cast<const bf16x8*>(zrb + m * 256 + (((kc * 4 + quad) ^ (m & 7)) * 8));
        }
        #pragma unroll
        for (int i = 0; i < 4; ++i)
            #pragma unroll
            for (int j = 0; j < 4; ++j)
                acc[i][j] = __builtin_amdgcn_mfma_f32_16x16x32_bf16(wf[i][kc], bfv[j], acc[i][j], 0, 0, 0);
    }
    __syncthreads();   // all zrb reads done before hz overwrite ordering w/ writeback
    #pragma unroll
    for (int i = 0; i < 4; ++i) {
        int n2b = wave * 64 + i * 16 + quad * 4;
        float4 bb = *reinterpret_cast<const float4*>(b2 + n2b);
        #pragma unroll
        for (int j = 0; j < 4; ++j) {
            int m = j * 16 + fr;
            float vm = (nodes[row0 + m] >= 0) ? 1.0f : 0.0f;
            ushort4 o = { f2us((acc[i][j][0] + bb.x) * vm),
                          f2us((acc[i][j][1] + bb.y) * vm),
                          f2us((acc[i][j][2] + bb.z) * vm),
                          f2us((acc[i][j][3] + bb.w) * vm) };
            *reinterpret_cast<ushort4*>(hz + m * 256 + (((n2b >> 3) ^ (m & 7)) * 8) + (n2b & 7)) = o;
        }
    }
    __syncthreads();

    // ---- write back 32 KB, coalesced (unswizzle) ----
    #pragma unroll
    for (int it = 0; it < 8; ++it) {
        int t16 = it * 256 + tid;          // 16B chunk id, 2048 total
        int r = t16 >> 5, g = t16 & 31;
        *reinterpret_cast<uint4*>(h + (size_t)(row0 + r) * 256 + g * 8) =
            *reinterpret_cast<const uint4*>(hz + r * 256 + ((g ^ (r & 7)) * 8));
    }
}

// ---------------------------------------------------------------------------
// 64x64-tile bf16 MFMA GEMM for latency-bound transformer GEMMs.
// 4 waves (2x2), each 32x32. dbuf global_load_lds staging, 16 KB LDS.
__global__ __launch_bounds__(256) void k_tgemm64(
    const u16* __restrict__ A, const u16* __restrict__ BT,
    const float* __restrict__ bias, void* __restrict__ Cout, int c_is_bf16,
    const float* __restrict__ resid, const int* __restrict__ valid,
    int M, int K, int N, int act)
{
    __shared__ __align__(16) u16 As[2][64 * 32];   // 4 KB each buf
    __shared__ __align__(16) u16 Bs[2][64 * 32];
    int tid = threadIdx.x, lane = tid & 63, wave = tid >> 6;
    int wm = wave >> 1, wn = wave & 1;
    int bm = blockIdx.y * 64, bn = blockIdx.x * 64;
    const u16* gA = A + (size_t)(bm + wave * 16 + (lane >> 2)) * K + (lane & 3) * 8;
    const u16* gB = BT + (size_t)(bn + wave * 16 + (lane >> 2)) * K + (lane & 3) * 8;
    gll16(gA, &As[0][wave * 512]);
    gll16(gB, &Bs[0][wave * 512]);
    f32x4 acc[2][2];
    #pragma unroll
    for (int i = 0; i < 2; ++i)
        #pragma unroll
        for (int j = 0; j < 2; ++j) acc[i][j] = (f32x4){0.f, 0.f, 0.f, 0.f};
    int fr = lane & 15, quad = lane >> 4;
    int nit = K >> 5;
    __syncthreads();
    for (int it = 0; it < nit; ++it) {
        int buf = it & 1;
        if (it + 1 < nit) {
            int k0 = (it + 1) * 32;
            gll16(gA + k0, &As[buf ^ 1][wave * 512]);
            gll16(gB + k0, &Bs[buf ^ 1][wave * 512]);
        }
        bf16x8 af[2], bfr[2];
        #pragma unroll
        for (int i = 0; i < 2; ++i)
            af[i] = *reinterpret_cast<const bf16x8*>(&As[buf][(wm * 32 + i * 16 + fr) * 32 + quad * 8]);
        #pragma unroll
        for (int j = 0; j < 2; ++j)
            bfr[j] = *reinterpret_cast<const bf16x8*>(&Bs[buf][(wn * 32 + j * 16 + fr) * 32 + quad * 8]);
        #pragma unroll
        for (int i = 0; i < 2; ++i)
            #pragma unroll
            for (int j = 0; j < 2; ++j)
                acc[i][j] = __builtin_amdgcn_mfma_f32_16x16x32_bf16(af[i], bfr[j], acc[i][j], 0, 0, 0);
        __syncthreads();
    }
    int crow0 = bm + wm * 32 + quad * 4;
    int ccol0 = bn + wn * 32 + fr;
    #pragma unroll
    for (int i = 0; i < 2; ++i) {
        #pragma unroll
        for (int r = 0; r < 4; ++r) {
            int m = crow0 + i * 16 + r;
            float vm = valid ? ((valid[m] >= 0) ? 1.0f : 0.0f) : 1.0f;
            #pragma unroll
            for (int j = 0; j < 2; ++j) {
                int n = ccol0 + j * 16;
                float v = acc[i][j][r];
                if (bias) v += bias[n];
                if (act == 1) v = v > 0.f ? v : 0.f;
                else if (act == 2) v = 0.5f * v * (1.0f + erff(v * 0.70710678118654752f));
                v *= vm;
                if (resid) v += resid[(size_t)m * N + n];
                if (c_is_bf16) ((u16*)Cout)[(size_t)m * N + n] = f2us(v);
                else ((float*)Cout)[(size_t)m * N + n] = v;
            }
        }
    }
}

// ---------------------------------------------------------------------------
// Row LayerNorm: 4 rows/block (one per wave), reads f32 x, writes bf16.
__global__ __launch_bounds__(256) void k_ln(
    const float* __restrict__ X, u16* __restrict__ Out,
    const float* __restrict__ g, const float* __restrict__ b)
{
    int row = blockIdx.x * 4 + (threadIdx.x >> 6);
    int lane = threadIdx.x & 63;
    float4 xv = *reinterpret_cast<const float4*>(X + (size_t)row * HDIM + lane * 4);
    float s = xv.x + xv.y + xv.z + xv.w;
    #pragma unroll
    for (int off = 32; off > 0; off >>= 1) s += __shfl_xor(s, off);
    float mu = s * (1.0f / HDIM);
    float d0 = xv.x - mu, d1 = xv.y - mu, d2 = xv.z - mu, d3 = xv.w - mu;
    float sq = d0 * d0 + d1 * d1 + d2 * d2 + d3 * d3;
    #pragma unroll
    for (int off = 32; off > 0; off >>= 1) sq += __shfl_xor(sq, off);
    float rs = rsqrtf(sq * (1.0f / HDIM) + 1e-5f);
    int c = lane * 4;
    float4 gv = *reinterpret_cast<const float4*>(g + c);
    float4 bv = *reinterpret_cast<const float4*>(b + c);
    ushort4 o = { f2us(d0 * rs * gv.x + bv.x), f2us(d1 * rs * gv.y + bv.y),
                  f2us(d2 * rs * gv.z + bv.z), f2us(d3 * rs * gv.w + bv.w) };
    *reinterpret_cast<ushort4*>(Out + (size_t)row * HDIM + c) = o;
}

// ---------------------------------------------------------------------------
// Overlap bias via 512-bit LDS bitmaps (node ids < 500).
__global__ __launch_bounds__(1024) void k_bias(
    const int* __restrict__ nodes, const float* __restrict__ lp,
    const float* __restrict__ ovl_emb, const float* __restrict__ alpha_p,
    float* __restrict__ bias)
{
    int b = blockIdx.x, tid = threadIdx.x;
    __shared__ int nd[32][32];
    __shared__ unsigned int bmv[32][17];
    __shared__ float lpc[32];
    __shared__ float emb[16];
    nd[tid >> 5][tid & 31] = nodes[b * 1024 + tid];
    if (tid < 512) bmv[tid >> 4][tid & 15] = 0u;
    if (tid < 32) {
        float l = finite_or_zero(lp[b * 32 + tid]);
        l = l < -30.f ? -30.f : (l > 0.f ? 0.f : l);
        lpc[tid] = l;
    }
    if (tid >= 64 && tid < 64 + KMAXC + 1) emb[tid - 64] = ovl_emb[tid - 64];
    __syncthreads();
    int own = nd[tid >> 5][tid & 31];
    if (own >= 0) atomicOr(&bmv[tid >> 5][own >> 5], 1u << (own & 31));
    __syncthreads();
    int i = tid >> 5, j = tid & 31;
    float alpha = alpha_p[0];
    int cnt = 0;
    #pragma unroll
    for (int k = 0; k < 32; ++k) {
        int nk = nd[i][k];
        if (nk >= 0) cnt += (int)((bmv[j][nk >> 5] >> (nk & 31)) & 1u);
    }
    bias[b * 1024 + tid] = emb[cnt > KMAXC ? KMAXC : cnt] - alpha * lpc[j];
}

// ---------------------------------------------------------------------------
__global__ __launch_bounds__(256) void k_gather(const u16* __restrict__ h, float* __restrict__ x)
{
    int s = blockIdx.x, c = threadIdx.x;
    x[(size_t)s * HDIM + c] = us2f(h[(size_t)s * KNODE * HDIM + c]);
}

// ---------------------------------------------------------------------------
// Attention for one (batch b, head hh): 32x32 scores with bias, softmax, PV.
__global__ __launch_bounds__(256) void k_attn(
    const u16* __restrict__ qkv, const float* __restrict__ bias, u16* __restrict__ o)
{
    int b = blockIdx.x >> 2, hh = blockIdx.x & 3;
    __shared__ float qs[32][65], ks[32][65], vs[32][65];
    __shared__ float sc[32][33];
    int tid = threadIdx.x;
    #pragma unroll
    for (int u = 0; u < 8; ++u) {
        int idx = tid + u * 256;
        int i = idx >> 6, d = idx & 63;
        size_t base = (size_t)(b * 32 + i) * 768;
        qs[i][d] = us2f(qkv[base + hh * 64 + d]);
        ks[i][d] = us2f(qkv[base + 256 + hh * 64 + d]);
        vs[i][d] = us2f(qkv[base + 512 + hh * 64 + d]);
    }
    __syncthreads();
    #pragma unroll
    for (int u = 0; u < 4; ++u) {
        int p = tid + u * 256;
        int i = p >> 5, j = p & 31;
        float s = 0.f;
        #pragma unroll
        for (int d = 0; d < 64; ++d) s += qs[i][d] * ks[j][d];
        sc[i][j] = s * 0.125f + bias[b * 1024 + i * 32 + j];
    }
    __syncthreads();
    if (tid < 32) {
        int i = tid;
        float m = -1e30f;
        for (int j = 0; j < 32; ++j) m = fmaxf(m, sc[i][j]);
        float sum = 0.f;
        for (int j = 0; j < 32; ++j) { float e = expf(sc[i][j] - m); sc[i][j] = e; sum += e; }
        float inv = 1.0f / sum;
        for (int j = 0; j < 32; ++j) sc[i][j] *= inv;
    }
    __syncthreads();
    #pragma unroll
    for (int u = 0; u < 8; ++u) {
        int idx = tid + u * 256;
        int i = idx >> 6, d = idx & 63;
        float a = 0.f;
        #pragma unroll
        for (int j = 0; j < 32; ++j) a += sc[i][j] * vs[j][d];
        o[(size_t)(b * 32 + i) * HDIM + hh * 64 + d] = f2us(a);
    }
}

// ---------------------------------------------------------------------------
// out[b] = sum_i softmax(-lp_c)[i] * xln[b,i,:]  (f32 output)
__global__ __launch_bounds__(256) void k_final(
    const u16* __restrict__ xln, const float* __restrict__ lp, float* __restrict__ out)
{
    int b = blockIdx.x, tid = threadIdx.x;
    __shared__ float w[32];
    if (tid < 32) {
        float l = finite_or_zero(lp[b * 32 + tid]);
        l = l < -30.f ? -30.f : (l > 0.f ? 0.f : l);
        w[tid] = -l;
    }
    __syncthreads();
    if (tid == 0) {
        float m = -1e30f;
        for (int i = 0; i < 32; ++i) m = fmaxf(m, w[i]);
        float s = 0.f;
        for (int i = 0; i < 32; ++i) { float e = expf(w[i] - m); w[i] = e; s += e; }
        float inv = 1.0f / s;
        for (int i = 0; i < 32; ++i) w[i] *= inv;
    }
    __syncthreads();
    float acc = 0.f;
    for (int i = 0; i < 32; ++i) acc += w[i] * us2f(xln[(size_t)(b * 32 + i) * HDIM + tid]);
    out[b * HDIM + tid] = acc;
}

// ---------------------------------------------------------------------------
extern "C" void kernel_launch(void* const* d_in, const int* in_sizes, int n_in,
                              void* d_out, int out_size, void* d_ws, size_t ws_size,
                              hipStream_t stream)
{
    const int*   x_ids    = (const int*)d_in[0];
    const int*   edge_ids = (const int*)d_in[1];
    const int*   srcp     = (const int*)d_in[2];
    const int*   dstp     = (const int*)d_in[3];
    const int*   nodes    = (const int*)d_in[4];
    const int*   dist     = (const int*)d_in[5];
    const float* lp       = (const float*)d_in[6];
    const float* atom_emb = (const float*)d_in[7];
    const float* bond_emb = (const float*)d_in[8];
    const float* dist_emb = (const float*)d_in[9];
    const float* logp_W   = (const float*)d_in[10];
    const float* logp_b   = (const float*)d_in[11];
    const float* gnn_eps  = (const float*)d_in[12];
    const float* gnn_W1   = (const float*)d_in[13];
    const float* gnn_b1   = (const float*)d_in[14];
    const float* gnn_W2   = (const float*)d_in[15];
    const float* gnn_b2   = (const float*)d_in[16];
    const float* ln1_g    = (const float*)d_in[17];
    const float* ln1_b    = (const float*)d_in[18];
    const float* qkv_W    = (const float*)d_in[19];
    const float* out_W    = (const float*)d_in[20];
    const float* out_b    = (const float*)d_in[21];
    const float* ln2_g    = (const float*)d_in[22];
    const float* ln2_b    = (const float*)d_in[23];
    const float* f1_W     = (const float*)d_in[24];
    const float* f1_b     = (const float*)d_in[25];
    const float* f2_W     = (const float*)d_in[26];
    const float* f2_b     = (const float*)d_in[27];
    const float* lnout_g  = (const float*)d_in[28];
    const float* lnout_b  = (const float*)d_in[29];
    const float* ovl_emb  = (const float*)d_in[30];
    const float* alpha    = (const float*)d_in[31];

    char* ws = (char*)d_ws;
    u16*   h     = (u16*)(ws);
    u16*   gW1T  = (u16*)(ws + 100663296ull);                // 512 KB
    u16*   gW2T  = (u16*)(ws + 100663296ull + 524288ull);    // 512 KB
    // transformer scratch (z region, dead during GNN):
    u16*   r     = (u16*)(ws + 33554432ull);                 // 1 MB
    u16*   ob    = (u16*)(ws + 33554432ull + 1048576ull);    // 1 MB
    u16*   qkvb  = (u16*)(ws + 33554432ull + 2097152ull);    // 3 MB
    u16*   ffh   = (u16*)(ws + 33554432ull + 5242880ull);    // 4 MB
    u16*   xln   = (u16*)(ws + 33554432ull + 9437184ull);    // 1 MB
    float* biasb = (float*)(ws + 33554432ull + 10485760ull); // 256 KB
    u16*   qkvT  = (u16*)(ws + 33554432ull + 11534336ull);   // 1.5 MB
    u16*   outT  = (u16*)(ws + 33554432ull + 13107200ull);   // 512 KB
    u16*   f1T   = (u16*)(ws + 33554432ull + 13631488ull);   // 2 MB
    u16*   f2T   = (u16*)(ws + 33554432ull + 15728640ull);   // 2 MB
    float* x     = (float*)(ws + 67108864ull);               // 2 MB f32

    k_wtrans<<<dim3(8, 8, 4), 256, 0, stream>>>(gnn_W1, gW1T, 256, 256);
    k_wtrans<<<dim3(8, 8, 4), 256, 0, stream>>>(gnn_W2, gW2T, 256, 256);
    k_init_h<<<NNODE / 4, 256, 0, stream>>>(x_ids, dist, nodes, lp, atom_emb, dist_emb,
                                            logp_W, logp_b, h);
    for (int l = 0; l < LLAY; ++l) {
        k_gnn<<<NNODE / 64, 256, 0, stream>>>(
            h, srcp, dstp, edge_ids, bond_emb, gnn_eps, l,
            gnn_b1 + l * HDIM, gnn_b2 + l * HDIM,
            gW1T + l * 65536, gW2T + l * 65536, nodes);
    }
    k_wtrans<<<dim3(8, 24, 4), 256, 0, stream>>>(qkv_W, qkvT, 256, 768);
    k_wtrans<<<dim3(8, 8, 4), 256, 0, stream>>>(out_W, outT, 256, 256);
    k_wtrans<<<dim3(8, 32, 4), 256, 0, stream>>>(f1_W, f1T, 256, 1024);
    k_wtrans<<<dim3(32, 8, 4), 256, 0, stream>>>(f2_W, f2T, 1024, 256);
    k_bias<<<BATCH, 1024, 0, stream>>>(nodes, lp, ovl_emb, alpha, biasb);
    k_gather<<<SSUB, 256, 0, stream>>>(h, x);
    for (int t = 0; t < TLAY; ++t) {
        k_ln<<<SSUB / 4, 256, 0, stream>>>(x, r, ln1_g + t * HDIM, ln1_b + t * HDIM);
        k_tgemm64<<<dim3(12, SSUB / 64), 256, 0, stream>>>(
            r, qkvT + t * 768 * 256, nullptr, qkvb, 1,
            nullptr, nullptr, SSUB, 256, 768, 0);
        k_attn<<<BATCH * NHEAD, 256, 0, stream>>>(qkvb, biasb, ob);
        k_tgemm64<<<dim3(4, SSUB / 64), 256, 0, stream>>>(
            ob, outT + t * 65536, out_b + t * HDIM, x, 0,
            x, nullptr, SSUB, 256, HDIM, 0);
        k_ln<<<SSUB / 4, 256, 0, stream>>>(x, r, ln2_g + t * HDIM, ln2_b + t * HDIM);
        k_tgemm64<<<dim3(16, SSUB / 64), 256, 0, stream>>>(
            r, f1T + t * 1024 * 256, f1_b + t * 1024, ffh, 1,
            nullptr, nullptr, SSUB, 256, 1024, 2);
        k_tgemm64<<<dim3(4, SSUB / 64), 256, 0, stream>>>(
            ffh, f2T + t * 256 * 1024, f2_b + t * HDIM, x, 0,
            x, nullptr, SSUB, 1024, HDIM, 0);
    }
    k_ln<<<SSUB / 4, 256, 0, stream>>>(x, xln, lnout_g, lnout_b);
    k_final<<<BATCH, 256, 0, stream>>>(xln, lp, (float*)d_out);
}

// Round 8
// 663.847 us; speedup vs baseline: 2.0147x; 1.0217x over previous
//
#include <hip/hip_runtime.h>
#include <hip/hip_bf16.h>
#include <math.h>

// Sizes from the reference
#define HDIM   256
#define NHEAD  4
#define LLAY   4
#define TLAY   4
#define KMAXC  10
#define MAXD   32
#define BATCH  64
#define MSUB   32
#define KNODE  32
#define SSUB   2048     // BATCH*MSUB
#define NNODE  65536    // SSUB*KNODE
#define NEDGE  131072
#define EPSPER 64       // NEDGE/SSUB
#define EDN    5

typedef unsigned short u16;   // raw bf16 bits (internal staging only)
typedef __attribute__((ext_vector_type(8))) short bf16x8;
typedef __attribute__((ext_vector_type(4))) float f32x4;

__device__ __forceinline__ float us2f(u16 u) {
    union { unsigned int i; float f; } x; x.i = ((unsigned int)u) << 16; return x.f;
}
__device__ __forceinline__ u16 f2us(float v) {
    union { float f; unsigned int i; } x; x.f = v;
    unsigned int u = x.i;
    u += 0x7fffu + ((u >> 16) & 1u);   // RNE
    return (u16)(u >> 16);
}
__device__ __forceinline__ float finite_or_zero(float v) {
    return (v == v && fabsf(v) <= 3.0e38f) ? v : 0.0f;
}
// async global->LDS, 16B per lane; lds base wave-uniform, lane deposits at +lane*16
__device__ __forceinline__ void gll16(const u16* g, u16* l) {
    __builtin_amdgcn_global_load_lds(
        (const __attribute__((address_space(1))) unsigned int*)g,
        (__attribute__((address_space(3))) unsigned int*)l, 16, 0, 0);
}

// ---------------------------------------------------------------------------
// CSR precompute: per subgraph, edges sorted by local dst row.
// perm[s*64+j] = (src_local<<3)|eid ; off[s*32+r] = start of row r (end of
// row 31 is 64). One wave per subgraph; within-dst edge order preserved.
__global__ __launch_bounds__(256) void k_csr(
    const int* __restrict__ src, const int* __restrict__ dst,
    const int* __restrict__ eid, u16* __restrict__ perm, u16* __restrict__ off)
{
    __shared__ int sL[4][64], dL[4][64], eL[4][64];
    int wave = threadIdx.x >> 6, lane = threadIdx.x & 63;
    int sgi = blockIdx.x * 4 + wave;
    sL[wave][lane] = src[sgi * 64 + lane] - sgi * KNODE;
    dL[wave][lane] = dst[sgi * 64 + lane] - sgi * KNODE;
    eL[wave][lane] = eid[sgi * 64 + lane];
    __syncthreads();
    if (lane < 32) {
        int cnt = 0;
        for (int e = 0; e < 64; ++e) cnt += (dL[wave][e] == lane) ? 1 : 0;
        int incl = cnt;
        #pragma unroll
        for (int d = 1; d < 32; d <<= 1) {
            int v = __shfl_up(incl, d, 64);
            if (lane >= d) incl += v;
        }
        int start = incl - cnt;
        off[sgi * 32 + lane] = (u16)start;
        int pos = start;
        for (int e = 0; e < 64; ++e) {
            if (dL[wave][e] == lane) {
                perm[sgi * 64 + pos] = (u16)((sL[wave][e] << 3) | eL[wave][e]);
                ++pos;
            }
        }
    }
}

// ---------------------------------------------------------------------------
// Weight transpose+convert: W (K x N f32, slice z) -> WT (N x K bf16).
__global__ __launch_bounds__(256) void k_wtrans(
    const float* __restrict__ W, u16* __restrict__ WT, int K, int N)
{
    __shared__ float til[32][33];
    int k0 = blockIdx.x * 32, n0 = blockIdx.y * 32, s = blockIdx.z;
    const float* Wb = W + (size_t)s * K * N;
    u16* Tb = WT + (size_t)s * N * K;
    int j = threadIdx.x & 31, i0 = threadIdx.x >> 5;
    #pragma unroll
    for (int it = 0; it < 4; ++it) {
        int i = i0 + it * 8;
        til[i][j] = Wb[(size_t)(k0 + i) * N + n0 + j];
    }
    __syncthreads();
    #pragma unroll
    for (int it = 0; it < 4; ++it) {
        int i = i0 + it * 8;
        Tb[(size_t)(n0 + i) * K + k0 + j] = f2us(til[j][i]);
    }
}

// ---------------------------------------------------------------------------
// h init: 4 rows/block, vectorized.
__global__ __launch_bounds__(256) void k_init_h(
    const int* __restrict__ x_ids, const int* __restrict__ dist,
    const int* __restrict__ nodes, const float* __restrict__ lp,
    const float* __restrict__ atom_emb, const float* __restrict__ dist_emb,
    const float* __restrict__ logp_W, const float* __restrict__ logp_b,
    u16* __restrict__ h)
{
    int n = blockIdx.x * 4 + (threadIdx.x >> 6);
    int c = (threadIdx.x & 63) * 4;
    float valid = (nodes[n] >= 0) ? 1.0f : 0.0f;
    float lpv = finite_or_zero(lp[n >> 5]);
    int dc = dist[n]; dc = dc < 0 ? 0 : (dc > MAXD ? MAXD : dc);
    float4 wv = *reinterpret_cast<const float4*>(logp_W + c);
    float4 bv = *reinterpret_cast<const float4*>(logp_b + c);
    float4 av = *reinterpret_cast<const float4*>(atom_emb + x_ids[n] * HDIM + c);
    float4 dv = *reinterpret_cast<const float4*>(dist_emb + dc * HDIM + c);
    float p0 = fmaxf(lpv * wv.x + bv.x, 0.f), p1 = fmaxf(lpv * wv.y + bv.y, 0.f);
    float p2 = fmaxf(lpv * wv.z + bv.z, 0.f), p3 = fmaxf(lpv * wv.w + bv.w, 0.f);
    ushort4 o = { f2us((av.x + dv.x + p0) * valid), f2us((av.y + dv.y + p1) * valid),
                  f2us((av.z + dv.z + p2) * valid), f2us((av.w + dv.w + p3) * valid) };
    *reinterpret_cast<ushort4*>(h + (size_t)n * HDIM + c) = o;
}

// ---------------------------------------------------------------------------
// Fused GNN layer v3: one block = 2 subgraphs = 64 rows, in place, 4 blocks/CU.
// LDS 38.3 KB: [0,32K) hz (XOR-swizzled; serves z, zr, h' sequentially),
// [32K,37K) bond, then perm/off. Weights in registers. Phase E uses the CSR
// edge ordering: thread = (row, 32-col group), REGISTER accumulation -> no
// LDS RMW chains. Swizzle: elem (r,c) at r*512B + ((((c>>3))^(r&7))*16 + (c&7)*2).
__global__ __launch_bounds__(256, 4) void k_gnn(
    u16* __restrict__ h, const u16* __restrict__ perm, const u16* __restrict__ off,
    const float* __restrict__ bond_emb, const float* __restrict__ eps_arr, int layer,
    const float* __restrict__ b1, const float* __restrict__ b2,
    const u16* __restrict__ W1T, const u16* __restrict__ W2T,
    const int* __restrict__ nodes)
{
    __shared__ __align__(16) unsigned char smem[38784];
    u16*   hz    = (u16*)smem;                        // 32 KB
    float* bondL = (float*)(smem + 32768);            // 5 KB
    u16*   permL = (u16*)(smem + 32768 + 5120);       // 128 u16
    u16*   offL  = (u16*)(smem + 32768 + 5120 + 256); // 64 u16

    int tid = threadIdx.x, lane = tid & 63, wave = tid >> 6;
    int row0 = blockIdx.x * 64;
    int fr = lane & 15, quad = lane >> 4;

    // ---- stage hz (swizzled) + bond + CSR lists ----
    #pragma unroll
    for (int t = 0; t < 8; ++t) {
        int v = wave * 8 + t;               // 1KB segment = 2 rows
        int r = v * 2 + (lane >> 5);
        int g = (lane & 31) ^ (r & 7);
        gll16(h + (size_t)(row0 + r) * 256 + g * 8, (u16*)(smem + v * 1024));
    }
    for (int i = tid; i < EDN * 256; i += 256) bondL[i] = bond_emb[i];
    if (tid < 128) permL[tid] = perm[blockIdx.x * 128 + tid];
    if (tid < 64)  offL[tid]  = off[blockIdx.x * 64 + tid];
    float ep1 = 1.0f + eps_arr[layer];
    __syncthreads();

    // ---- phase E: CSR register accumulation, row-ownership ----
    int rl = tid >> 3, g8 = tid & 7;        // row-local (0..31), col-group (x32)
    for (int p = 0; p < 2; ++p) {
        int row = p * 32 + rl;
        int e0 = offL[p * 32 + rl];
        int e1 = (rl < 31) ? offL[p * 32 + rl + 1] : 64;
        float a[32];
        #pragma unroll
        for (int q = 0; q < 32; ++q) a[q] = 0.f;
        for (int j = e0; j < e1; ++j) {
            int ent = permL[p * 64 + j];
            int sl = p * 32 + (ent >> 3);
            int be = ent & 7;
            #pragma unroll
            for (int q = 0; q < 4; ++q) {
                union { bf16x8 v; u16 s[8]; } hv;
                hv.v = *reinterpret_cast<const bf16x8*>(
                    hz + sl * 256 + (((g8 * 4 + q) ^ (sl & 7)) * 8));
                const float* bp = bondL + be * 256 + g8 * 32 + q * 8;
                float4 bo0 = *reinterpret_cast<const float4*>(bp);
                float4 bo1 = *reinterpret_cast<const float4*>(bp + 4);
                a[q*8+0] += fmaxf(us2f(hv.s[0]) + bo0.x, 0.f);
                a[q*8+1] += fmaxf(us2f(hv.s[1]) + bo0.y, 0.f);
                a[q*8+2] += fmaxf(us2f(hv.s[2]) + bo0.z, 0.f);
                a[q*8+3] += fmaxf(us2f(hv.s[3]) + bo0.w, 0.f);
                a[q*8+4] += fmaxf(us2f(hv.s[4]) + bo1.x, 0.f);
                a[q*8+5] += fmaxf(us2f(hv.s[5]) + bo1.y, 0.f);
                a[q*8+6] += fmaxf(us2f(hv.s[6]) + bo1.z, 0.f);
                a[q*8+7] += fmaxf(us2f(hv.s[7]) + bo1.w, 0.f);
            }
        }
        __syncthreads();   // all reads of subgraph p's h complete before z writes
        #pragma unroll
        for (int q = 0; q < 4; ++q) {
            u16* ptr = hz + row * 256 + (((g8 * 4 + q) ^ (row & 7)) * 8);
            union { bf16x8 v; u16 s[8]; } hv, ov;
            hv.v = *reinterpret_cast<const bf16x8*>(ptr);
            #pragma unroll
            for (int k = 0; k < 8; ++k)
                ov.s[k] = f2us(ep1 * us2f(hv.s[k]) + a[q * 8 + k]);
            *reinterpret_cast<bf16x8*>(ptr) = ov.v;
        }
    }
    __syncthreads();

    // ---- phase 1: zr = relu(z @ W1 + b1), zr aliases hz ----
    bf16x8 wf[4][8];
    #pragma unroll
    for (int i = 0; i < 4; ++i)
        #pragma unroll
        for (int kc = 0; kc < 8; ++kc)
            wf[i][kc] = *reinterpret_cast<const bf16x8*>(
                W1T + (size_t)(wave * 64 + i * 16 + fr) * 256 + kc * 32 + quad * 8);
    f32x4 acc[4][4];
    #pragma unroll
    for (int i = 0; i < 4; ++i)
        #pragma unroll
        for (int j = 0; j < 4; ++j) acc[i][j] = (f32x4){0.f, 0.f, 0.f, 0.f};
    #pragma unroll
    for (int kc = 0; kc < 8; ++kc) {
        bf16x8 bfv[4];
        #pragma unroll
        for (int j = 0; j < 4; ++j) {
            int m = j * 16 + fr;
            bfv[j] = *reinterpret_cast<const bf16x8*>(hz + m * 256 + (((kc * 4 + quad) ^ (m & 7)) * 8));
        }
        #pragma unroll
        for (int i = 0; i < 4; ++i)
            #pragma unroll
            for (int j = 0; j < 4; ++j)
                acc[i][j] = __builtin_amdgcn_mfma_f32_16x16x32_bf16(wf[i][kc], bfv[j], acc[i][j], 0, 0, 0);
    }
    __syncthreads();   // all z reads done before zr overwrites hz
    #pragma unroll
    for (int i = 0; i < 4; ++i) {
        int n1b = wave * 64 + i * 16 + quad * 4;
        float4 bb = *reinterpret_cast<const float4*>(b1 + n1b);
        #pragma unroll
        for (int j = 0; j < 4; ++j) {
            int m = j * 16 + fr;
            ushort4 o = { f2us(fmaxf(acc[i][j][0] + bb.x, 0.f)),
                          f2us(fmaxf(acc[i][j][1] + bb.y, 0.f)),
                          f2us(fmaxf(acc[i][j][2] + bb.z, 0.f)),
                          f2us(fmaxf(acc[i][j][3] + bb.w, 0.f)) };
            *reinterpret_cast<ushort4*>(hz + m * 256 + (((n1b >> 3) ^ (m & 7)) * 8) + (n1b & 7)) = o;
        }
    }
    __syncthreads();

    // ---- phase 2: h' = (zr @ W2 + b2) * valid, h' aliases hz ----
    #pragma unroll
    for (int i = 0; i < 4; ++i)
        #pragma unroll
        for (int kc = 0; kc < 8; ++kc)
            wf[i][kc] = *reinterpret_cast<const bf16x8*>(
                W2T + (size_t)(wave * 64 + i * 16 + fr) * 256 + kc * 32 + quad * 8);
    #pragma unroll
    for (int i = 0; i < 4; ++i)
        #pragma unroll
        for (int j = 0; j < 4; ++j) acc[i][j] = (f32x4){0.f, 0.f, 0.f, 0.f};
    #pragma unroll
    for (int kc = 0; kc < 8; ++kc) {
        bf16x8 bfv[4];
        #pragma unroll
        for (int j = 0; j < 4; ++j) {
            int m = j * 16 + fr;
            bfv[j] = *reinterpret_cast<const bf16x8*>(hz + m * 256 + (((kc * 4 + quad) ^ (m & 7)) * 8));
        }
        #pragma unroll
        for (int i = 0; i < 4; ++i)
            #pragma unroll
            for (int j = 0; j < 4; ++j)
                acc[i][j] = __builtin_amdgcn_mfma_f32_16x16x32_bf16(wf[i][kc], bfv[j], acc[i][j], 0, 0, 0);
    }
    __syncthreads();   // all zr reads done before h' overwrites hz
    #pragma unroll
    for (int i = 0; i < 4; ++i) {
        int n2b = wave * 64 + i * 16 + quad * 4;
        float4 bb = *reinterpret_cast<const float4*>(b2 + n2b);
        #pragma unroll
        for (int j = 0; j < 4; ++j) {
            int m = j * 16 + fr;
            float vm = (nodes[row0 + m] >= 0) ? 1.0f : 0.0f;
            ushort4 o = { f2us((acc[i][j][0] + bb.x) * vm),
                          f2us((acc[i][j][1] + bb.y) * vm),
                          f2us((acc[i][j][2] + bb.z) * vm),
                          f2us((acc[i][j][3] + bb.w) * vm) };
            *reinterpret_cast<ushort4*>(hz + m * 256 + (((n2b >> 3) ^ (m & 7)) * 8) + (n2b & 7)) = o;
        }
    }
    __syncthreads();

    // ---- write back 32 KB, coalesced (unswizzle) ----
    #pragma unroll
    for (int it = 0; it < 8; ++it) {
        int t16 = it * 256 + tid;          // 16B chunk id, 2048 total
        int r = t16 >> 5, g = t16 & 31;
        *reinterpret_cast<uint4*>(h + (size_t)(row0 + r) * 256 + g * 8) =
            *reinterpret_cast<const uint4*>(hz + r * 256 + ((g ^ (r & 7)) * 8));
    }
}

// ---------------------------------------------------------------------------
// 64x64-tile bf16 MFMA GEMM for latency-bound transformer GEMMs.
__global__ __launch_bounds__(256) void k_tgemm64(
    const u16* __restrict__ A, const u16* __restrict__ BT,
    const float* __restrict__ bias, void* __restrict__ Cout, int c_is_bf16,
    const float* __restrict__ resid, const int* __restrict__ valid,
    int M, int K, int N, int act)
{
    __shared__ __align__(16) u16 As[2][64 * 32];
    __shared__ __align__(16) u16 Bs[2][64 * 32];
    int tid = threadIdx.x, lane = tid & 63, wave = tid >> 6;
    int wm = wave >> 1, wn = wave & 1;
    int bm = blockIdx.y * 64, bn = blockIdx.x * 64;
    const u16* gA = A + (size_t)(bm + wave * 16 + (lane >> 2)) * K + (lane & 3) * 8;
    const u16* gB = BT + (size_t)(bn + wave * 16 + (lane >> 2)) * K + (lane & 3) * 8;
    gll16(gA, &As[0][wave * 512]);
    gll16(gB, &Bs[0][wave * 512]);
    f32x4 acc[2][2];
    #pragma unroll
    for (int i = 0; i < 2; ++i)
        #pragma unroll
        for (int j = 0; j < 2; ++j) acc[i][j] = (f32x4){0.f, 0.f, 0.f, 0.f};
    int fr = lane & 15, quad = lane >> 4;
    int nit = K >> 5;
    __syncthreads();
    for (int it = 0; it < nit; ++it) {
        int buf = it & 1;
        if (it + 1 < nit) {
            int k0 = (it + 1) * 32;
            gll16(gA + k0, &As[buf ^ 1][wave * 512]);
            gll16(gB + k0, &Bs[buf ^ 1][wave * 512]);
        }
        bf16x8 af[2], bfr[2];
        #pragma unroll
        for (int i = 0; i < 2; ++i)
            af[i] = *reinterpret_cast<const bf16x8*>(&As[buf][(wm * 32 + i * 16 + fr) * 32 + quad * 8]);
        #pragma unroll
        for (int j = 0; j < 2; ++j)
            bfr[j] = *reinterpret_cast<const bf16x8*>(&Bs[buf][(wn * 32 + j * 16 + fr) * 32 + quad * 8]);
        #pragma unroll
        for (int i = 0; i < 2; ++i)
            #pragma unroll
            for (int j = 0; j < 2; ++j)
                acc[i][j] = __builtin_amdgcn_mfma_f32_16x16x32_bf16(af[i], bfr[j], acc[i][j], 0, 0, 0);
        __syncthreads();
    }
    int crow0 = bm + wm * 32 + quad * 4;
    int ccol0 = bn + wn * 32 + fr;
    #pragma unroll
    for (int i = 0; i < 2; ++i) {
        #pragma unroll
        for (int r = 0; r < 4; ++r) {
            int m = crow0 + i * 16 + r;
            float vm = valid ? ((valid[m] >= 0) ? 1.0f : 0.0f) : 1.0f;
            #pragma unroll
            for (int j = 0; j < 2; ++j) {
                int n = ccol0 + j * 16;
                float v = acc[i][j][r];
                if (bias) v += bias[n];
                if (act == 1) v = v > 0.f ? v : 0.f;
                else if (act == 2) v = 0.5f * v * (1.0f + erff(v * 0.70710678118654752f));
                v *= vm;
                if (resid) v += resid[(size_t)m * N + n];
                if (c_is_bf16) ((u16*)Cout)[(size_t)m * N + n] = f2us(v);
                else ((float*)Cout)[(size_t)m * N + n] = v;
            }
        }
    }
}

// ---------------------------------------------------------------------------
// Row LayerNorm: 4 rows/block (one per wave), reads f32 x, writes bf16.
__global__ __launch_bounds__(256) void k_ln(
    const float* __restrict__ X, u16* __restrict__ Out,
    const float* __restrict__ g, const float* __restrict__ b)
{
    int row = blockIdx.x * 4 + (threadIdx.x >> 6);
    int lane = threadIdx.x & 63;
    float4 xv = *reinterpret_cast<const float4*>(X + (size_t)row * HDIM + lane * 4);
    float s = xv.x + xv.y + xv.z + xv.w;
    #pragma unroll
    for (int off = 32; off > 0; off >>= 1) s += __shfl_xor(s, off);
    float mu = s * (1.0f / HDIM);
    float d0 = xv.x - mu, d1 = xv.y - mu, d2 = xv.z - mu, d3 = xv.w - mu;
    float sq = d0 * d0 + d1 * d1 + d2 * d2 + d3 * d3;
    #pragma unroll
    for (int off = 32; off > 0; off >>= 1) sq += __shfl_xor(sq, off);
    float rs = rsqrtf(sq * (1.0f / HDIM) + 1e-5f);
    int c = lane * 4;
    float4 gv = *reinterpret_cast<const float4*>(g + c);
    float4 bv = *reinterpret_cast<const float4*>(b + c);
    ushort4 o = { f2us(d0 * rs * gv.x + bv.x), f2us(d1 * rs * gv.y + bv.y),
                  f2us(d2 * rs * gv.z + bv.z), f2us(d3 * rs * gv.w + bv.w) };
    *reinterpret_cast<ushort4*>(Out + (size_t)row * HDIM + c) = o;
}

// ---------------------------------------------------------------------------
// Overlap bias via 512-bit LDS bitmaps (node ids < 500).
__global__ __launch_bounds__(1024) void k_bias(
    const int* __restrict__ nodes, const float* __restrict__ lp,
    const float* __restrict__ ovl_emb, const float* __restrict__ alpha_p,
    float* __restrict__ bias)
{
    int b = blockIdx.x, tid = threadIdx.x;
    __shared__ int nd[32][32];
    __shared__ unsigned int bmv[32][17];
    __shared__ float lpc[32];
    __shared__ float emb[16];
    nd[tid >> 5][tid & 31] = nodes[b * 1024 + tid];
    if (tid < 512) bmv[tid >> 4][tid & 15] = 0u;
    if (tid < 32) {
        float l = finite_or_zero(lp[b * 32 + tid]);
        l = l < -30.f ? -30.f : (l > 0.f ? 0.f : l);
        lpc[tid] = l;
    }
    if (tid >= 64 && tid < 64 + KMAXC + 1) emb[tid - 64] = ovl_emb[tid - 64];
    __syncthreads();
    int own = nd[tid >> 5][tid & 31];
    if (own >= 0) atomicOr(&bmv[tid >> 5][own >> 5], 1u << (own & 31));
    __syncthreads();
    int i = tid >> 5, j = tid & 31;
    float alpha = alpha_p[0];
    int cnt = 0;
    #pragma unroll
    for (int k = 0; k < 32; ++k) {
        int nk = nd[i][k];
        if (nk >= 0) cnt += (int)((bmv[j][nk >> 5] >> (nk & 31)) & 1u);
    }
    bias[b * 1024 + tid] = emb[cnt > KMAXC ? KMAXC : cnt] - alpha * lpc[j];
}

// ---------------------------------------------------------------------------
__global__ __launch_bounds__(256) void k_gather(const u16* __restrict__ h, float* __restrict__ x)
{
    int s = blockIdx.x, c = threadIdx.x;
    x[(size_t)s * HDIM + c] = us2f(h[(size_t)s * KNODE * HDIM + c]);
}

// ---------------------------------------------------------------------------
// Attention for one (batch b, head hh): 32x32 scores with bias, softmax, PV.
__global__ __launch_bounds__(256) void k_attn(
    const u16* __restrict__ qkv, const float* __restrict__ bias, u16* __restrict__ o)
{
    int b = blockIdx.x >> 2, hh = blockIdx.x & 3;
    __shared__ float qs[32][65], ks[32][65], vs[32][65];
    __shared__ float sc[32][33];
    int tid = threadIdx.x;
    #pragma unroll
    for (int u = 0; u < 8; ++u) {
        int idx = tid + u * 256;
        int i = idx >> 6, d = idx & 63;
        size_t base = (size_t)(b * 32 + i) * 768;
        qs[i][d] = us2f(qkv[base + hh * 64 + d]);
        ks[i][d] = us2f(qkv[base + 256 + hh * 64 + d]);
        vs[i][d] = us2f(qkv[base + 512 + hh * 64 + d]);
    }
    __syncthreads();
    #pragma unroll
    for (int u = 0; u < 4; ++u) {
        int p = tid + u * 256;
        int i = p >> 5, j = p & 31;
        float s = 0.f;
        #pragma unroll
        for (int d = 0; d < 64; ++d) s += qs[i][d] * ks[j][d];
        sc[i][j] = s * 0.125f + bias[b * 1024 + i * 32 + j];
    }
    __syncthreads();
    if (tid < 32) {
        int i = tid;
        float m = -1e30f;
        for (int j = 0; j < 32; ++j) m = fmaxf(m, sc[i][j]);
        float sum = 0.f;
        for (int j = 0; j < 32; ++j) { float e = expf(sc[i][j] - m); sc[i][j] = e; sum += e; }
        float inv = 1.0f / sum;
        for (int j = 0; j < 32; ++j) sc[i][j] *= inv;
    }
    __syncthreads();
    #pragma unroll
    for (int u = 0; u < 8; ++u) {
        int idx = tid + u * 256;
        int i = idx >> 6, d = idx & 63;
        float a = 0.f;
        #pragma unroll
        for (int j = 0; j < 32; ++j) a += sc[i][j] * vs[j][d];
        o[(size_t)(b * 32 + i) * HDIM + hh * 64 + d] = f2us(a);
    }
}

// ---------------------------------------------------------------------------
// out[b] = sum_i softmax(-lp_c)[i] * xln[b,i,:]  (f32 output)
__global__ __launch_bounds__(256) void k_final(
    const u16* __restrict__ xln, const float* __restrict__ lp, float* __restrict__ out)
{
    int b = blockIdx.x, tid = threadIdx.x;
    __shared__ float w[32];
    if (tid < 32) {
        float l = finite_or_zero(lp[b * 32 + tid]);
        l = l < -30.f ? -30.f : (l > 0.f ? 0.f : l);
        w[tid] = -l;
    }
    __syncthreads();
    if (tid == 0) {
        float m = -1e30f;
        for (int i = 0; i < 32; ++i) m = fmaxf(m, w[i]);
        float s = 0.f;
        for (int i = 0; i < 32; ++i) { float e = expf(w[i] - m); w[i] = e; s += e; }
        float inv = 1.0f / s;
        for (int i = 0; i < 32; ++i) w[i] *= inv;
    }
    __syncthreads();
    float acc = 0.f;
    for (int i = 0; i < 32; ++i) acc += w[i] * us2f(xln[(size_t)(b * 32 + i) * HDIM + tid]);
    out[b * HDIM + tid] = acc;
}

// ---------------------------------------------------------------------------
extern "C" void kernel_launch(void* const* d_in, const int* in_sizes, int n_in,
                              void* d_out, int out_size, void* d_ws, size_t ws_size,
                              hipStream_t stream)
{
    const int*   x_ids    = (const int*)d_in[0];
    const int*   edge_ids = (const int*)d_in[1];
    const int*   srcp     = (const int*)d_in[2];
    const int*   dstp     = (const int*)d_in[3];
    const int*   nodes    = (const int*)d_in[4];
    const int*   dist     = (const int*)d_in[5];
    const float* lp       = (const float*)d_in[6];
    const float* atom_emb = (const float*)d_in[7];
    const float* bond_emb = (const float*)d_in[8];
    const float* dist_emb = (const float*)d_in[9];
    const float* logp_W   = (const float*)d_in[10];
    const float* logp_b   = (const float*)d_in[11];
    const float* gnn_eps  = (const float*)d_in[12];
    const float* gnn_W1   = (const float*)d_in[13];
    const float* gnn_b1   = (const float*)d_in[14];
    const float* gnn_W2   = (const float*)d_in[15];
    const float* gnn_b2   = (const float*)d_in[16];
    const float* ln1_g    = (const float*)d_in[17];
    const float* ln1_b    = (const float*)d_in[18];
    const float* qkv_W    = (const float*)d_in[19];
    const float* out_W    = (const float*)d_in[20];
    const float* out_b    = (const float*)d_in[21];
    const float* ln2_g    = (const float*)d_in[22];
    const float* ln2_b    = (const float*)d_in[23];
    const float* f1_W     = (const float*)d_in[24];
    const float* f1_b     = (const float*)d_in[25];
    const float* f2_W     = (const float*)d_in[26];
    const float* f2_b     = (const float*)d_in[27];
    const float* lnout_g  = (const float*)d_in[28];
    const float* lnout_b  = (const float*)d_in[29];
    const float* ovl_emb  = (const float*)d_in[30];
    const float* alpha    = (const float*)d_in[31];

    char* ws = (char*)d_ws;
    u16*   h     = (u16*)(ws);
    u16*   gW1T  = (u16*)(ws + 100663296ull);                // 512 KB
    u16*   gW2T  = (u16*)(ws + 100663296ull + 524288ull);    // 512 KB
    u16*   permW = (u16*)(ws + 100663296ull + 1048576ull);   // 256 KB
    u16*   offW  = (u16*)(ws + 100663296ull + 1310720ull);   // 128 KB
    // transformer scratch (z region, dead during GNN):
    u16*   r     = (u16*)(ws + 33554432ull);                 // 1 MB
    u16*   ob    = (u16*)(ws + 33554432ull + 1048576ull);    // 1 MB
    u16*   qkvb  = (u16*)(ws + 33554432ull + 2097152ull);    // 3 MB
    u16*   ffh   = (u16*)(ws + 33554432ull + 5242880ull);    // 4 MB
    u16*   xln   = (u16*)(ws + 33554432ull + 9437184ull);    // 1 MB
    float* biasb = (float*)(ws + 33554432ull + 10485760ull); // 256 KB
    u16*   qkvT  = (u16*)(ws + 33554432ull + 11534336ull);   // 1.5 MB
    u16*   outT  = (u16*)(ws + 33554432ull + 13107200ull);   // 512 KB
    u16*   f1T   = (u16*)(ws + 33554432ull + 13631488ull);   // 2 MB
    u16*   f2T   = (u16*)(ws + 33554432ull + 15728640ull);   // 2 MB
    float* x     = (float*)(ws + 67108864ull);               // 2 MB f32

    k_csr<<<SSUB / 4, 256, 0, stream>>>(srcp, dstp, edge_ids, permW, offW);
    k_wtrans<<<dim3(8, 8, 4), 256, 0, stream>>>(gnn_W1, gW1T, 256, 256);
    k_wtrans<<<dim3(8, 8, 4), 256, 0, stream>>>(gnn_W2, gW2T, 256, 256);
    k_init_h<<<NNODE / 4, 256, 0, stream>>>(x_ids, dist, nodes, lp, atom_emb, dist_emb,
                                            logp_W, logp_b, h);
    for (int l = 0; l < LLAY; ++l) {
        k_gnn<<<NNODE / 64, 256, 0, stream>>>(
            h, permW, offW, bond_emb, gnn_eps, l,
            gnn_b1 + l * HDIM, gnn_b2 + l * HDIM,
            gW1T + l * 65536, gW2T + l * 65536, nodes);
    }
    k_wtrans<<<dim3(8, 24, 4), 256, 0, stream>>>(qkv_W, qkvT, 256, 768);
    k_wtrans<<<dim3(8, 8, 4), 256, 0, stream>>>(out_W, outT, 256, 256);
    k_wtrans<<<dim3(8, 32, 4), 256, 0, stream>>>(f1_W, f1T, 256, 1024);
    k_wtrans<<<dim3(32, 8, 4), 256, 0, stream>>>(f2_W, f2T, 1024, 256);
    k_bias<<<BATCH, 1024, 0, stream>>>(nodes, lp, ovl_emb, alpha, biasb);
    k_gather<<<SSUB, 256, 0, stream>>>(h, x);
    for (int t = 0; t < TLAY; ++t) {
        k_ln<<<SSUB / 4, 256, 0, stream>>>(x, r, ln1_g + t * HDIM, ln1_b + t * HDIM);
        k_tgemm64<<<dim3(12, SSUB / 64), 256, 0, stream>>>(
            r, qkvT + t * 768 * 256, nullptr, qkvb, 1,
            nullptr, nullptr, SSUB, 256, 768, 0);
        k_attn<<<BATCH * NHEAD, 256, 0, stream>>>(qkvb, biasb, ob);
        k_tgemm64<<<dim3(4, SSUB / 64), 256, 0, stream>>>(
            ob, outT + t * 65536, out_b + t * HDIM, x, 0,
            x, nullptr, SSUB, 256, HDIM, 0);
        k_ln<<<SSUB / 4, 256, 0, stream>>>(x, r, ln2_g + t * HDIM, ln2_b + t * HDIM);
        k_tgemm64<<<dim3(16, SSUB / 64), 256, 0, stream>>>(
            r, f1T + t * 1024 * 256, f1_b + t * 1024, ffh, 1,
            nullptr, nullptr, SSUB, 256, 1024, 2);
        k_tgemm64<<<dim3(4, SSUB / 64), 256, 0, stream>>>(
            ffh, f2T + t * 256 * 1024, f2_b + t * HDIM, x, 0,
            x, nullptr, SSUB, 1024, HDIM, 0);
    }
    k_ln<<<SSUB / 4, 256, 0, stream>>>(x, xln, lnout_g, lnout_b);
    k_final<<<BATCH, 256, 0, stream>>>(xln, lp, (float*)d_out);
}

// Round 9
// 587.109 us; speedup vs baseline: 2.2780x; 1.1307x over previous
//
#include <hip/hip_runtime.h>
#include <hip/hip_bf16.h>
#include <math.h>

// Sizes from the reference
#define HDIM   256
#define NHEAD  4
#define LLAY   4
#define TLAY   4
#define KMAXC  10
#define MAXD   32
#define BATCH  64
#define MSUB   32
#define KNODE  32
#define SSUB   2048     // BATCH*MSUB
#define NNODE  65536    // SSUB*KNODE
#define NEDGE  131072
#define EPSPER 64       // NEDGE/SSUB
#define EDN    5

typedef unsigned short u16;   // raw bf16 bits (internal staging only)
typedef __attribute__((ext_vector_type(8))) short bf16x8;
typedef __attribute__((ext_vector_type(4))) float f32x4;

__device__ __forceinline__ float us2f(u16 u) {
    union { unsigned int i; float f; } x; x.i = ((unsigned int)u) << 16; return x.f;
}
__device__ __forceinline__ u16 f2us(float v) {
    union { float f; unsigned int i; } x; x.f = v;
    unsigned int u = x.i;
    u += 0x7fffu + ((u >> 16) & 1u);   // RNE
    return (u16)(u >> 16);
}
__device__ __forceinline__ float finite_or_zero(float v) {
    return (v == v && fabsf(v) <= 3.0e38f) ? v : 0.0f;
}
// async global->LDS, 16B per lane; lds base wave-uniform, lane deposits at +lane*16
__device__ __forceinline__ void gll16(const u16* g, u16* l) {
    __builtin_amdgcn_global_load_lds(
        (const __attribute__((address_space(1))) unsigned int*)g,
        (__attribute__((address_space(3))) unsigned int*)l, 16, 0, 0);
}

// ---------------------------------------------------------------------------
// CSR precompute: per subgraph, edges sorted by local dst row.
__global__ __launch_bounds__(256) void k_csr(
    const int* __restrict__ src, const int* __restrict__ dst,
    const int* __restrict__ eid, u16* __restrict__ perm, u16* __restrict__ off)
{
    __shared__ int sL[4][64], dL[4][64], eL[4][64];
    int wave = threadIdx.x >> 6, lane = threadIdx.x & 63;
    int sgi = blockIdx.x * 4 + wave;
    sL[wave][lane] = src[sgi * 64 + lane] - sgi * KNODE;
    dL[wave][lane] = dst[sgi * 64 + lane] - sgi * KNODE;
    eL[wave][lane] = eid[sgi * 64 + lane];
    __syncthreads();
    if (lane < 32) {
        int cnt = 0;
        for (int e = 0; e < 64; ++e) cnt += (dL[wave][e] == lane) ? 1 : 0;
        int incl = cnt;
        #pragma unroll
        for (int d = 1; d < 32; d <<= 1) {
            int v = __shfl_up(incl, d, 64);
            if (lane >= d) incl += v;
        }
        int start = incl - cnt;
        off[sgi * 32 + lane] = (u16)start;
        int pos = start;
        for (int e = 0; e < 64; ++e) {
            if (dL[wave][e] == lane) {
                perm[sgi * 64 + pos] = (u16)((sL[wave][e] << 3) | eL[wave][e]);
                ++pos;
            }
        }
    }
}

// ---------------------------------------------------------------------------
// Weight transpose+convert: W (K x N f32, slice z) -> WT (N x K bf16).
__global__ __launch_bounds__(256) void k_wtrans(
    const float* __restrict__ W, u16* __restrict__ WT, int K, int N)
{
    __shared__ float til[32][33];
    int k0 = blockIdx.x * 32, n0 = blockIdx.y * 32, s = blockIdx.z;
    const float* Wb = W + (size_t)s * K * N;
    u16* Tb = WT + (size_t)s * N * K;
    int j = threadIdx.x & 31, i0 = threadIdx.x >> 5;
    #pragma unroll
    for (int it = 0; it < 4; ++it) {
        int i = i0 + it * 8;
        til[i][j] = Wb[(size_t)(k0 + i) * N + n0 + j];
    }
    __syncthreads();
    #pragma unroll
    for (int it = 0; it < 4; ++it) {
        int i = i0 + it * 8;
        Tb[(size_t)(n0 + i) * K + k0 + j] = f2us(til[j][i]);
    }
}

// ---------------------------------------------------------------------------
// Fully-fused GNN: h-init + ALL 4 layers + root-row extraction in ONE kernel.
// One block = 2 subgraphs = 64 rows, LDS-resident the whole time, 4 blocks/CU.
// No cross-block deps (edges are subgraph-local; only h[root] consumed after).
// hz swizzle: elem (r,c) at r*512B + ((((c>>3))^(r&7))*16 + (c&7)*2).
// Output: x[s*256 + :] f32 for the 2 root rows (s = blockIdx*2 + {0,1}).
__global__ __launch_bounds__(256, 4) void k_gnn4(
    const int* __restrict__ x_ids, const int* __restrict__ dist,
    const int* __restrict__ nodes, const float* __restrict__ lp,
    const float* __restrict__ atom_emb, const float* __restrict__ dist_emb,
    const float* __restrict__ logp_W, const float* __restrict__ logp_b,
    const u16* __restrict__ perm, const u16* __restrict__ off,
    const float* __restrict__ bond_emb, const float* __restrict__ eps_arr,
    const float* __restrict__ b1a, const float* __restrict__ b2a,
    const u16* __restrict__ W1T, const u16* __restrict__ W2T,
    float* __restrict__ x)
{
    __shared__ __align__(16) unsigned char smem[38912];
    u16*   hz    = (u16*)smem;                        // 32 KB
    float* bondL = (float*)(smem + 32768);            // 5 KB
    u16*   permL = (u16*)(smem + 32768 + 5120);       // 128 u16
    u16*   offL  = (u16*)(smem + 32768 + 5120 + 256); // 64 u16
    float* validL= (float*)(smem + 32768 + 5120 + 512);  // 64 f32
    float* epsL  = (float*)(smem + 32768 + 5120 + 512 + 256); // 4 f32

    int tid = threadIdx.x, lane = tid & 63, wave = tid >> 6;
    int row0 = blockIdx.x * 64;
    int fr = lane & 15, quad = lane >> 4;

    // ---- stage bond/CSR/valid/eps ----
    for (int i = tid; i < EDN * 256; i += 256) bondL[i] = bond_emb[i];
    if (tid < 128) permL[tid] = perm[blockIdx.x * 128 + tid];
    if (tid < 64) {
        offL[tid] = off[blockIdx.x * 64 + tid];
        validL[tid] = (nodes[row0 + tid] >= 0) ? 1.0f : 0.0f;
    }
    if (tid < 4) epsL[tid] = eps_arr[tid];

    // ---- h init directly into hz (4 threads/row, 64 cols each) ----
    {
        int m = tid & 63, qd = tid >> 6;
        int rg = row0 + m;
        float valid = (nodes[rg] >= 0) ? 1.0f : 0.0f;
        float lpv = finite_or_zero(lp[rg >> 5]);
        int dc = dist[rg]; dc = dc < 0 ? 0 : (dc > MAXD ? MAXD : dc);
        int xid = x_ids[rg];
        #pragma unroll
        for (int k = 0; k < 8; ++k) {
            int cc = qd * 8 + k, c = cc * 8;
            float4 a0 = *reinterpret_cast<const float4*>(atom_emb + xid * 256 + c);
            float4 a1 = *reinterpret_cast<const float4*>(atom_emb + xid * 256 + c + 4);
            float4 d0 = *reinterpret_cast<const float4*>(dist_emb + dc * 256 + c);
            float4 d1 = *reinterpret_cast<const float4*>(dist_emb + dc * 256 + c + 4);
            float4 w0 = *reinterpret_cast<const float4*>(logp_W + c);
            float4 w1 = *reinterpret_cast<const float4*>(logp_W + c + 4);
            float4 p0 = *reinterpret_cast<const float4*>(logp_b + c);
            float4 p1 = *reinterpret_cast<const float4*>(logp_b + c + 4);
            union { bf16x8 v; ushort4 h[2]; } o;
            o.h[0] = (ushort4){
                f2us((a0.x + d0.x + fmaxf(lpv * w0.x + p0.x, 0.f)) * valid),
                f2us((a0.y + d0.y + fmaxf(lpv * w0.y + p0.y, 0.f)) * valid),
                f2us((a0.z + d0.z + fmaxf(lpv * w0.z + p0.z, 0.f)) * valid),
                f2us((a0.w + d0.w + fmaxf(lpv * w0.w + p0.w, 0.f)) * valid) };
            o.h[1] = (ushort4){
                f2us((a1.x + d1.x + fmaxf(lpv * w1.x + p1.x, 0.f)) * valid),
                f2us((a1.y + d1.y + fmaxf(lpv * w1.y + p1.y, 0.f)) * valid),
                f2us((a1.z + d1.z + fmaxf(lpv * w1.z + p1.z, 0.f)) * valid),
                f2us((a1.w + d1.w + fmaxf(lpv * w1.w + p1.w, 0.f)) * valid) };
            *reinterpret_cast<bf16x8*>(hz + m * 256 + ((cc ^ (m & 7)) * 8)) = o.v;
        }
    }
    __syncthreads();

    int rl = tid >> 3, g8 = tid & 7;        // phase E: row-local, col-group
    for (int l = 0; l < LLAY; ++l) {
        // ---- phase E: CSR register accumulation, row-ownership ----
        float ep1 = 1.0f + epsL[l];
        for (int p = 0; p < 2; ++p) {
            int row = p * 32 + rl;
            int e0 = offL[p * 32 + rl];
            int e1 = (rl < 31) ? offL[p * 32 + rl + 1] : 64;
            float a[32];
            #pragma unroll
            for (int q = 0; q < 32; ++q) a[q] = 0.f;
            for (int j = e0; j < e1; ++j) {
                int ent = permL[p * 64 + j];
                int sl = p * 32 + (ent >> 3);
                int be = ent & 7;
                #pragma unroll
                for (int q = 0; q < 4; ++q) {
                    union { bf16x8 v; u16 s[8]; } hv;
                    hv.v = *reinterpret_cast<const bf16x8*>(
                        hz + sl * 256 + (((g8 * 4 + q) ^ (sl & 7)) * 8));
                    const float* bp = bondL + be * 256 + g8 * 32 + q * 8;
                    float4 bo0 = *reinterpret_cast<const float4*>(bp);
                    float4 bo1 = *reinterpret_cast<const float4*>(bp + 4);
                    a[q*8+0] += fmaxf(us2f(hv.s[0]) + bo0.x, 0.f);
                    a[q*8+1] += fmaxf(us2f(hv.s[1]) + bo0.y, 0.f);
                    a[q*8+2] += fmaxf(us2f(hv.s[2]) + bo0.z, 0.f);
                    a[q*8+3] += fmaxf(us2f(hv.s[3]) + bo0.w, 0.f);
                    a[q*8+4] += fmaxf(us2f(hv.s[4]) + bo1.x, 0.f);
                    a[q*8+5] += fmaxf(us2f(hv.s[5]) + bo1.y, 0.f);
                    a[q*8+6] += fmaxf(us2f(hv.s[6]) + bo1.z, 0.f);
                    a[q*8+7] += fmaxf(us2f(hv.s[7]) + bo1.w, 0.f);
                }
            }
            __syncthreads();   // all reads of subgraph p's h done before z writes
            #pragma unroll
            for (int q = 0; q < 4; ++q) {
                u16* ptr = hz + row * 256 + (((g8 * 4 + q) ^ (row & 7)) * 8);
                union { bf16x8 v; u16 s[8]; } hv, ov;
                hv.v = *reinterpret_cast<const bf16x8*>(ptr);
                #pragma unroll
                for (int k = 0; k < 8; ++k)
                    ov.s[k] = f2us(ep1 * us2f(hv.s[k]) + a[q * 8 + k]);
                *reinterpret_cast<bf16x8*>(ptr) = ov.v;
            }
        }
        __syncthreads();

        // ---- phase 1: zr = relu(z @ W1 + b1), zr aliases hz ----
        const u16* W1 = W1T + l * 65536;
        const float* b1 = b1a + l * 256;
        bf16x8 wf[4][8];
        #pragma unroll
        for (int i = 0; i < 4; ++i)
            #pragma unroll
            for (int kc = 0; kc < 8; ++kc)
                wf[i][kc] = *reinterpret_cast<const bf16x8*>(
                    W1 + (size_t)(wave * 64 + i * 16 + fr) * 256 + kc * 32 + quad * 8);
        f32x4 acc[4][4];
        #pragma unroll
        for (int i = 0; i < 4; ++i)
            #pragma unroll
            for (int j = 0; j < 4; ++j) acc[i][j] = (f32x4){0.f, 0.f, 0.f, 0.f};
        #pragma unroll
        for (int kc = 0; kc < 8; ++kc) {
            bf16x8 bfv[4];
            #pragma unroll
            for (int j = 0; j < 4; ++j) {
                int m = j * 16 + fr;
                bfv[j] = *reinterpret_cast<const bf16x8*>(hz + m * 256 + (((kc * 4 + quad) ^ (m & 7)) * 8));
            }
            #pragma unroll
            for (int i = 0; i < 4; ++i)
                #pragma unroll
                for (int j = 0; j < 4; ++j)
                    acc[i][j] = __builtin_amdgcn_mfma_f32_16x16x32_bf16(wf[i][kc], bfv[j], acc[i][j], 0, 0, 0);
        }
        __syncthreads();   // all z reads done before zr overwrites hz
        #pragma unroll
        for (int i = 0; i < 4; ++i) {
            int n1b = wave * 64 + i * 16 + quad * 4;
            float4 bb = *reinterpret_cast<const float4*>(b1 + n1b);
            #pragma unroll
            for (int j = 0; j < 4; ++j) {
                int m = j * 16 + fr;
                ushort4 o = { f2us(fmaxf(acc[i][j][0] + bb.x, 0.f)),
                              f2us(fmaxf(acc[i][j][1] + bb.y, 0.f)),
                              f2us(fmaxf(acc[i][j][2] + bb.z, 0.f)),
                              f2us(fmaxf(acc[i][j][3] + bb.w, 0.f)) };
                *reinterpret_cast<ushort4*>(hz + m * 256 + (((n1b >> 3) ^ (m & 7)) * 8) + (n1b & 7)) = o;
            }
        }
        __syncthreads();

        // ---- phase 2: h' = (zr @ W2 + b2) * valid ----
        const u16* W2 = W2T + l * 65536;
        const float* b2 = b2a + l * 256;
        #pragma unroll
        for (int i = 0; i < 4; ++i)
            #pragma unroll
            for (int kc = 0; kc < 8; ++kc)
                wf[i][kc] = *reinterpret_cast<const bf16x8*>(
                    W2 + (size_t)(wave * 64 + i * 16 + fr) * 256 + kc * 32 + quad * 8);
        #pragma unroll
        for (int i = 0; i < 4; ++i)
            #pragma unroll
            for (int j = 0; j < 4; ++j) acc[i][j] = (f32x4){0.f, 0.f, 0.f, 0.f};
        #pragma unroll
        for (int kc = 0; kc < 8; ++kc) {
            bf16x8 bfv[4];
            #pragma unroll
            for (int j = 0; j < 4; ++j) {
                int m = j * 16 + fr;
                bfv[j] = *reinterpret_cast<const bf16x8*>(hz + m * 256 + (((kc * 4 + quad) ^ (m & 7)) * 8));
            }
            #pragma unroll
            for (int i = 0; i < 4; ++i)
                #pragma unroll
                for (int j = 0; j < 4; ++j)
                    acc[i][j] = __builtin_amdgcn_mfma_f32_16x16x32_bf16(wf[i][kc], bfv[j], acc[i][j], 0, 0, 0);
        }
        __syncthreads();   // all zr reads done before h' overwrites hz

        if (l < LLAY - 1) {
            #pragma unroll
            for (int i = 0; i < 4; ++i) {
                int n2b = wave * 64 + i * 16 + quad * 4;
                float4 bb = *reinterpret_cast<const float4*>(b2 + n2b);
                #pragma unroll
                for (int j = 0; j < 4; ++j) {
                    int m = j * 16 + fr;
                    float vm = validL[m];
                    ushort4 o = { f2us((acc[i][j][0] + bb.x) * vm),
                                  f2us((acc[i][j][1] + bb.y) * vm),
                                  f2us((acc[i][j][2] + bb.z) * vm),
                                  f2us((acc[i][j][3] + bb.w) * vm) };
                    *reinterpret_cast<ushort4*>(hz + m * 256 + (((n2b >> 3) ^ (m & 7)) * 8) + (n2b & 7)) = o;
                }
            }
            __syncthreads();
        } else {
            // last layer: only root rows (m=0, m=32) matter -> write x directly
            if (fr == 0) {
                #pragma unroll
                for (int i = 0; i < 4; ++i) {
                    int n2b = wave * 64 + i * 16 + quad * 4;
                    float4 bb = *reinterpret_cast<const float4*>(b2 + n2b);
                    #pragma unroll
                    for (int jj = 0; jj < 2; ++jj) {
                        int j = jj * 2, m = j * 16;          // m = 0, 32
                        float vm = validL[m];
                        float4 o = { (acc[i][j][0] + bb.x) * vm,
                                     (acc[i][j][1] + bb.y) * vm,
                                     (acc[i][j][2] + bb.z) * vm,
                                     (acc[i][j][3] + bb.w) * vm };
                        *reinterpret_cast<float4*>(
                            x + (size_t)(blockIdx.x * 2 + (m >> 5)) * 256 + n2b) = o;
                    }
                }
            }
        }
    }
}

// ---------------------------------------------------------------------------
// 64x64-tile bf16 MFMA GEMM for latency-bound transformer GEMMs.
__global__ __launch_bounds__(256) void k_tgemm64(
    const u16* __restrict__ A, const u16* __restrict__ BT,
    const float* __restrict__ bias, void* __restrict__ Cout, int c_is_bf16,
    const float* __restrict__ resid, const int* __restrict__ valid,
    int M, int K, int N, int act)
{
    __shared__ __align__(16) u16 As[2][64 * 32];
    __shared__ __align__(16) u16 Bs[2][64 * 32];
    int tid = threadIdx.x, lane = tid & 63, wave = tid >> 6;
    int wm = wave >> 1, wn = wave & 1;
    int bm = blockIdx.y * 64, bn = blockIdx.x * 64;
    const u16* gA = A + (size_t)(bm + wave * 16 + (lane >> 2)) * K + (lane & 3) * 8;
    const u16* gB = BT + (size_t)(bn + wave * 16 + (lane >> 2)) * K + (lane & 3) * 8;
    gll16(gA, &As[0][wave * 512]);
    gll16(gB, &Bs[0][wave * 512]);
    f32x4 acc[2][2];
    #pragma unroll
    for (int i = 0; i < 2; ++i)
        #pragma unroll
        for (int j = 0; j < 2; ++j) acc[i][j] = (f32x4){0.f, 0.f, 0.f, 0.f};
    int fr = lane & 15, quad = lane >> 4;
    int nit = K >> 5;
    __syncthreads();
    for (int it = 0; it < nit; ++it) {
        int buf = it & 1;
        if (it + 1 < nit) {
            int k0 = (it + 1) * 32;
            gll16(gA + k0, &As[buf ^ 1][wave * 512]);
            gll16(gB + k0, &Bs[buf ^ 1][wave * 512]);
        }
        bf16x8 af[2], bfr[2];
        #pragma unroll
        for (int i = 0; i < 2; ++i)
            af[i] = *reinterpret_cast<const bf16x8*>(&As[buf][(wm * 32 + i * 16 + fr) * 32 + quad * 8]);
        #pragma unroll
        for (int j = 0; j < 2; ++j)
            bfr[j] = *reinterpret_cast<const bf16x8*>(&Bs[buf][(wn * 32 + j * 16 + fr) * 32 + quad * 8]);
        #pragma unroll
        for (int i = 0; i < 2; ++i)
            #pragma unroll
            for (int j = 0; j < 2; ++j)
                acc[i][j] = __builtin_amdgcn_mfma_f32_16x16x32_bf16(af[i], bfr[j], acc[i][j], 0, 0, 0);
        __syncthreads();
    }
    int crow0 = bm + wm * 32 + quad * 4;
    int ccol0 = bn + wn * 32 + fr;
    #pragma unroll
    for (int i = 0; i < 2; ++i) {
        #pragma unroll
        for (int r = 0; r < 4; ++r) {
            int m = crow0 + i * 16 + r;
            float vm = valid ? ((valid[m] >= 0) ? 1.0f : 0.0f) : 1.0f;
            #pragma unroll
            for (int j = 0; j < 2; ++j) {
                int n = ccol0 + j * 16;
                float v = acc[i][j][r];
                if (bias) v += bias[n];
                if (act == 1) v = v > 0.f ? v : 0.f;
                else if (act == 2) v = 0.5f * v * (1.0f + erff(v * 0.70710678118654752f));
                v *= vm;
                if (resid) v += resid[(size_t)m * N + n];
                if (c_is_bf16) ((u16*)Cout)[(size_t)m * N + n] = f2us(v);
                else ((float*)Cout)[(size_t)m * N + n] = v;
            }
        }
    }
}

// ---------------------------------------------------------------------------
// Row LayerNorm: 4 rows/block (one per wave), reads f32 x, writes bf16.
__global__ __launch_bounds__(256) void k_ln(
    const float* __restrict__ X, u16* __restrict__ Out,
    const float* __restrict__ g, const float* __restrict__ b)
{
    int row = blockIdx.x * 4 + (threadIdx.x >> 6);
    int lane = threadIdx.x & 63;
    float4 xv = *reinterpret_cast<const float4*>(X + (size_t)row * HDIM + lane * 4);
    float s = xv.x + xv.y + xv.z + xv.w;
    #pragma unroll
    for (int off = 32; off > 0; off >>= 1) s += __shfl_xor(s, off);
    float mu = s * (1.0f / HDIM);
    float d0 = xv.x - mu, d1 = xv.y - mu, d2 = xv.z - mu, d3 = xv.w - mu;
    float sq = d0 * d0 + d1 * d1 + d2 * d2 + d3 * d3;
    #pragma unroll
    for (int off = 32; off > 0; off >>= 1) sq += __shfl_xor(sq, off);
    float rs = rsqrtf(sq * (1.0f / HDIM) + 1e-5f);
    int c = lane * 4;
    float4 gv = *reinterpret_cast<const float4*>(g + c);
    float4 bv = *reinterpret_cast<const float4*>(b + c);
    ushort4 o = { f2us(d0 * rs * gv.x + bv.x), f2us(d1 * rs * gv.y + bv.y),
                  f2us(d2 * rs * gv.z + bv.z), f2us(d3 * rs * gv.w + bv.w) };
    *reinterpret_cast<ushort4*>(Out + (size_t)row * HDIM + c) = o;
}

// ---------------------------------------------------------------------------
// Overlap bias via 512-bit LDS bitmaps (node ids < 500).
__global__ __launch_bounds__(1024) void k_bias(
    const int* __restrict__ nodes, const float* __restrict__ lp,
    const float* __restrict__ ovl_emb, const float* __restrict__ alpha_p,
    float* __restrict__ bias)
{
    int b = blockIdx.x, tid = threadIdx.x;
    __shared__ int nd[32][32];
    __shared__ unsigned int bmv[32][17];
    __shared__ float lpc[32];
    __shared__ float emb[16];
    nd[tid >> 5][tid & 31] = nodes[b * 1024 + tid];
    if (tid < 512) bmv[tid >> 4][tid & 15] = 0u;
    if (tid < 32) {
        float l = finite_or_zero(lp[b * 32 + tid]);
        l = l < -30.f ? -30.f : (l > 0.f ? 0.f : l);
        lpc[tid] = l;
    }
    if (tid >= 64 && tid < 64 + KMAXC + 1) emb[tid - 64] = ovl_emb[tid - 64];
    __syncthreads();
    int own = nd[tid >> 5][tid & 31];
    if (own >= 0) atomicOr(&bmv[tid >> 5][own >> 5], 1u << (own & 31));
    __syncthreads();
    int i = tid >> 5, j = tid & 31;
    float alpha = alpha_p[0];
    int cnt = 0;
    #pragma unroll
    for (int k = 0; k < 32; ++k) {
        int nk = nd[i][k];
        if (nk >= 0) cnt += (int)((bmv[j][nk >> 5] >> (nk & 31)) & 1u);
    }
    bias[b * 1024 + tid] = emb[cnt > KMAXC ? KMAXC : cnt] - alpha * lpc[j];
}

// ---------------------------------------------------------------------------
// Attention for one (batch b, head hh): 32x32 scores with bias, softmax, PV.
__global__ __launch_bounds__(256) void k_attn(
    const u16* __restrict__ qkv, const float* __restrict__ bias, u16* __restrict__ o)
{
    int b = blockIdx.x >> 2, hh = blockIdx.x & 3;
    __shared__ float qs[32][65], ks[32][65], vs[32][65];
    __shared__ float sc[32][33];
    int tid = threadIdx.x;
    #pragma unroll
    for (int u = 0; u < 8; ++u) {
        int idx = tid + u * 256;
        int i = idx >> 6, d = idx & 63;
        size_t base = (size_t)(b * 32 + i) * 768;
        qs[i][d] = us2f(qkv[base + hh * 64 + d]);
        ks[i][d] = us2f(qkv[base + 256 + hh * 64 + d]);
        vs[i][d] = us2f(qkv[base + 512 + hh * 64 + d]);
    }
    __syncthreads();
    #pragma unroll
    for (int u = 0; u < 4; ++u) {
        int p = tid + u * 256;
        int i = p >> 5, j = p & 31;
        float s = 0.f;
        #pragma unroll
        for (int d = 0; d < 64; ++d) s += qs[i][d] * ks[j][d];
        sc[i][j] = s * 0.125f + bias[b * 1024 + i * 32 + j];
    }
    __syncthreads();
    if (tid < 32) {
        int i = tid;
        float m = -1e30f;
        for (int j = 0; j < 32; ++j) m = fmaxf(m, sc[i][j]);
        float sum = 0.f;
        for (int j = 0; j < 32; ++j) { float e = expf(sc[i][j] - m); sc[i][j] = e; sum += e; }
        float inv = 1.0f / sum;
        for (int j = 0; j < 32; ++j) sc[i][j] *= inv;
    }
    __syncthreads();
    #pragma unroll
    for (int u = 0; u < 8; ++u) {
        int idx = tid + u * 256;
        int i = idx >> 6, d = idx & 63;
        float a = 0.f;
        #pragma unroll
        for (int j = 0; j < 32; ++j) a += sc[i][j] * vs[j][d];
        o[(size_t)(b * 32 + i) * HDIM + hh * 64 + d] = f2us(a);
    }
}

// ---------------------------------------------------------------------------
// out[b] = sum_i softmax(-lp_c)[i] * xln[b,i,:]  (f32 output)
__global__ __launch_bounds__(256) void k_final(
    const u16* __restrict__ xln, const float* __restrict__ lp, float* __restrict__ out)
{
    int b = blockIdx.x, tid = threadIdx.x;
    __shared__ float w[32];
    if (tid < 32) {
        float l = finite_or_zero(lp[b * 32 + tid]);
        l = l < -30.f ? -30.f : (l > 0.f ? 0.f : l);
        w[tid] = -l;
    }
    __syncthreads();
    if (tid == 0) {
        float m = -1e30f;
        for (int i = 0; i < 32; ++i) m = fmaxf(m, w[i]);
        float s = 0.f;
        for (int i = 0; i < 32; ++i) { float e = expf(w[i] - m); w[i] = e; s += e; }
        float inv = 1.0f / s;
        for (int i = 0; i < 32; ++i) w[i] *= inv;
    }
    __syncthreads();
    float acc = 0.f;
    for (int i = 0; i < 32; ++i) acc += w[i] * us2f(xln[(size_t)(b * 32 + i) * HDIM + tid]);
    out[b * HDIM + tid] = acc;
}

// ---------------------------------------------------------------------------
extern "C" void kernel_launch(void* const* d_in, const int* in_sizes, int n_in,
                              void* d_out, int out_size, void* d_ws, size_t ws_size,
                              hipStream_t stream)
{
    const int*   x_ids    = (const int*)d_in[0];
    const int*   edge_ids = (const int*)d_in[1];
    const int*   srcp     = (const int*)d_in[2];
    const int*   dstp     = (const int*)d_in[3];
    const int*   nodes    = (const int*)d_in[4];
    const int*   dist     = (const int*)d_in[5];
    const float* lp       = (const float*)d_in[6];
    const float* atom_emb = (const float*)d_in[7];
    const float* bond_emb = (const float*)d_in[8];
    const float* dist_emb = (const float*)d_in[9];
    const float* logp_W   = (const float*)d_in[10];
    const float* logp_b   = (const float*)d_in[11];
    const float* gnn_eps  = (const float*)d_in[12];
    const float* gnn_W1   = (const float*)d_in[13];
    const float* gnn_b1   = (const float*)d_in[14];
    const float* gnn_W2   = (const float*)d_in[15];
    const float* gnn_b2   = (const float*)d_in[16];
    const float* ln1_g    = (const float*)d_in[17];
    const float* ln1_b    = (const float*)d_in[18];
    const float* qkv_W    = (const float*)d_in[19];
    const float* out_W    = (const float*)d_in[20];
    const float* out_b    = (const float*)d_in[21];
    const float* ln2_g    = (const float*)d_in[22];
    const float* ln2_b    = (const float*)d_in[23];
    const float* f1_W     = (const float*)d_in[24];
    const float* f1_b     = (const float*)d_in[25];
    const float* f2_W     = (const float*)d_in[26];
    const float* f2_b     = (const float*)d_in[27];
    const float* lnout_g  = (const float*)d_in[28];
    const float* lnout_b  = (const float*)d_in[29];
    const float* ovl_emb  = (const float*)d_in[30];
    const float* alpha    = (const float*)d_in[31];

    char* ws = (char*)d_ws;
    u16*   gW1T  = (u16*)(ws + 100663296ull);                // 512 KB
    u16*   gW2T  = (u16*)(ws + 100663296ull + 524288ull);    // 512 KB
    u16*   permW = (u16*)(ws + 100663296ull + 1048576ull);   // 256 KB
    u16*   offW  = (u16*)(ws + 100663296ull + 1310720ull);   // 128 KB
    // transformer scratch:
    u16*   r     = (u16*)(ws + 33554432ull);                 // 1 MB
    u16*   ob    = (u16*)(ws + 33554432ull + 1048576ull);    // 1 MB
    u16*   qkvb  = (u16*)(ws + 33554432ull + 2097152ull);    // 3 MB
    u16*   ffh   = (u16*)(ws + 33554432ull + 5242880ull);    // 4 MB
    u16*   xln   = (u16*)(ws + 33554432ull + 9437184ull);    // 1 MB
    float* biasb = (float*)(ws + 33554432ull + 10485760ull); // 256 KB
    u16*   qkvT  = (u16*)(ws + 33554432ull + 11534336ull);   // 1.5 MB
    u16*   outT  = (u16*)(ws + 33554432ull + 13107200ull);   // 512 KB
    u16*   f1T   = (u16*)(ws + 33554432ull + 13631488ull);   // 2 MB
    u16*   f2T   = (u16*)(ws + 33554432ull + 15728640ull);   // 2 MB
    float* x     = (float*)(ws + 67108864ull);               // 2 MB f32

    k_csr<<<SSUB / 4, 256, 0, stream>>>(srcp, dstp, edge_ids, permW, offW);
    k_wtrans<<<dim3(8, 8, 4), 256, 0, stream>>>(gnn_W1, gW1T, 256, 256);
    k_wtrans<<<dim3(8, 8, 4), 256, 0, stream>>>(gnn_W2, gW2T, 256, 256);
    k_gnn4<<<NNODE / 64, 256, 0, stream>>>(
        x_ids, dist, nodes, lp, atom_emb, dist_emb, logp_W, logp_b,
        permW, offW, bond_emb, gnn_eps, gnn_b1, gnn_b2, gW1T, gW2T, x);
    k_wtrans<<<dim3(8, 24, 4), 256, 0, stream>>>(qkv_W, qkvT, 256, 768);
    k_wtrans<<<dim3(8, 8, 4), 256, 0, stream>>>(out_W, outT, 256, 256);
    k_wtrans<<<dim3(8, 32, 4), 256, 0, stream>>>(f1_W, f1T, 256, 1024);
    k_wtrans<<<dim3(32, 8, 4), 256, 0, stream>>>(f2_W, f2T, 1024, 256);
    k_bias<<<BATCH, 1024, 0, stream>>>(nodes, lp, ovl_emb, alpha, biasb);
    for (int t = 0; t < TLAY; ++t) {
        k_ln<<<SSUB / 4, 256, 0, stream>>>(x, r, ln1_g + t * HDIM, ln1_b + t * HDIM);
        k_tgemm64<<<dim3(12, SSUB / 64), 256, 0, stream>>>(
            r, qkvT + t * 768 * 256, nullptr, qkvb, 1,
            nullptr, nullptr, SSUB, 256, 768, 0);
        k_attn<<<BATCH * NHEAD, 256, 0, stream>>>(qkvb, biasb, ob);
        k_tgemm64<<<dim3(4, SSUB / 64), 256, 0, stream>>>(
            ob, outT + t * 65536, out_b + t * HDIM, x, 0,
            x, nullptr, SSUB, 256, HDIM, 0);
        k_ln<<<SSUB / 4, 256, 0, stream>>>(x, r, ln2_g + t * HDIM, ln2_b + t * HDIM);
        k_tgemm64<<<dim3(16, SSUB / 64), 256, 0, stream>>>(
            r, f1T + t * 1024 * 256, f1_b + t * 1024, ffh, 1,
            nullptr, nullptr, SSUB, 256, 1024, 2);
        k_tgemm64<<<dim3(4, SSUB / 64), 256, 0, stream>>>(
            ffh, f2T + t * 256 * 1024, f2_b + t * HDIM, x, 0,
            x, nullptr, SSUB, 1024, HDIM, 0);
    }
    k_ln<<<SSUB / 4, 256, 0, stream>>>(x, xln, lnout_g, lnout_b);
    k_final<<<BATCH, 256, 0, stream>>>(xln, lp, (float*)d_out);
}